// Round 7
// baseline (707.521 us; speedup 1.0000x reference)
//
#include <hip/hip_runtime.h>
#include <math.h>

// ---------------------------------------------------------------------------
// Problem: B=4, L=4096, D=P=256, tau=0.5
// out = (1/8) * sum_{b,l} [ log(S1-e^2) + log(S2-e^2) - 4*d[b,l] ]
//   S[b,q] = sum_{m<2L} exp(2 * Zhat[b,q].Zhat[b,m]),  Zhat = [z1n; z2n]
// Flash-gram R7: A-stripe in LDS (staged once, read per kc-step), B streamed
// global->VGPR (4-slot rotating prefetch), NO barriers in the hot loop.
// Grid 512 blocks (each does half the j-range) -> 2 blocks/CU, ~4 waves/SIMD
// (R6 lesson: A-in-regs burned 128 VGPRs -> 2 waves/SIMD, latency-bound).
// Partial rowsums -> S[4][8192] via atomics; tiny final_log_kernel does
// sum log(S - e2); d-term fused in the block owning the diagonal tile.
// ---------------------------------------------------------------------------

typedef __attribute__((ext_vector_type(8))) short short8;
typedef __attribute__((ext_vector_type(4))) short short4v;
typedef __attribute__((ext_vector_type(4))) float float4v;

__device__ __forceinline__ short f2bf(float f) {
    unsigned u = __builtin_bit_cast(unsigned, f);
    u += 0x7fffu + ((u >> 16) & 1u);          // RNE
    return (short)(u >> 16);
}

__device__ __forceinline__ void gl_lds16(const short* g, short* l) {
    __builtin_amdgcn_global_load_lds(
        (const __attribute__((address_space(1))) void*)g,
        (__attribute__((address_space(3))) void*)l, 16, 0, 0);
}

// ---------------------------------------------------------------------------
// 512-thread NT-GEMM core (verified R2/R3): C[RAxRB] = A*B^T, K=256.
// ---------------------------------------------------------------------------
template <int RA, int RB, int NWM>
__device__ __forceinline__ void gemm512_core(
    const short* __restrict__ A, const short* __restrict__ B,
    int arow0, int brow0, short* lsA, short* lsB, float4v acc[4][4])
{
    const int tid  = threadIdx.x;
    const int w    = tid >> 6;
    const int lane = tid & 63;
    const int wm   = w % NWM;
    const int wn   = w / NWM;
    constexpr int ACH = RA / 8;

    for (int kt = 0; kt < 4; ++kt) {
        const int kbase = kt * 64;
#pragma unroll
        for (int r = 0; r < 6; ++r) {
            const int c = w * 6 + r;
            if (c < ACH) {
                const int s   = c * 64 + lane;
                const int kc  = s / RA;
                const int row = s % RA;
                gl_lds16(A + (size_t)(arow0 + row) * 256 + kbase + kc * 8,
                         lsA + (size_t)c * 512);
            } else {
                const int s   = (c - ACH) * 64 + lane;
                const int kc  = s / RB;
                const int row = s % RB;
                gl_lds16(B + (size_t)(brow0 + row) * 256 + kbase + kc * 8,
                         lsB + (size_t)(c - ACH) * 512);
            }
        }
        __syncthreads();
#pragma unroll
        for (int ks = 0; ks < 2; ++ks) {
            const int kc = ks * 4 + (lane >> 4);
            short8 af[4], bfv[4];
#pragma unroll
            for (int mi = 0; mi < 4; ++mi)
                af[mi] = *(const short8*)(lsA + ((size_t)kc * RA + wm * 64 + mi * 16 + (lane & 15)) * 8);
#pragma unroll
            for (int ni = 0; ni < 4; ++ni)
                bfv[ni] = *(const short8*)(lsB + ((size_t)kc * RB + wn * 64 + ni * 16 + (lane & 15)) * 8);
#pragma unroll
            for (int mi = 0; mi < 4; ++mi)
#pragma unroll
                for (int ni = 0; ni < 4; ++ni)
                    acc[mi][ni] = __builtin_amdgcn_mfma_f32_16x16x32_bf16(
                        af[mi], bfv[ni], acc[mi][ni], 0, 0, 0);
        }
        __syncthreads();
    }
}

// ---------------------------------------------------------------------------
// fp32 -> bf16 converters
// ---------------------------------------------------------------------------
__global__ __launch_bounds__(256) void convX_kernel(
    const float* __restrict__ X1, const float* __restrict__ X2,
    short* __restrict__ dst)
{
    int i = blockIdx.x * 256 + threadIdx.x;
    const float* src = (i < 1048576) ? X1 : X2;
    int j = i & 1048575;
    float4v v = ((const float4v*)src)[j];
    short4v o;
    o.x = f2bf(v.x); o.y = f2bf(v.y); o.z = f2bf(v.z); o.w = f2bf(v.w);
    ((short4v*)dst)[i] = o;
}

__global__ __launch_bounds__(256) void convW_kernel(
    const float* __restrict__ W1, const float* __restrict__ W2,
    short* __restrict__ d1, short* __restrict__ d2)
{
    int i = blockIdx.x * 256 + threadIdx.x;
    const float* src = (i < 16384) ? W1 : W2;
    short* dst = (i < 16384) ? d1 : d2;
    int j = i & 16383;
    float4v v = ((const float4v*)src)[j];
    short4v o;
    o.x = f2bf(v.x); o.y = f2bf(v.y); o.z = f2bf(v.z); o.w = f2bf(v.w);
    ((short4v*)dst)[j] = o;
}

// ---------------------------------------------------------------------------
// proj1: H = elu(X*W1^T + b1) bf16, 32768x256, grid 256 x 512thr.
// ---------------------------------------------------------------------------
__global__ __launch_bounds__(512) void proj1_kernel(
    const short* __restrict__ Xbf, const short* __restrict__ W1bf,
    const float* __restrict__ b1, short* __restrict__ Hbf)
{
    __shared__ short lsA[8192];
    __shared__ short lsB[16384];
    const int arow0 = blockIdx.x * 128;
    float4v acc[4][4];
#pragma unroll
    for (int mi = 0; mi < 4; ++mi)
#pragma unroll
        for (int ni = 0; ni < 4; ++ni)
            acc[mi][ni] = (float4v){0.f, 0.f, 0.f, 0.f};

    gemm512_core<128, 256, 2>(Xbf, W1bf, arow0, 0, lsA, lsB, acc);

    const int tid  = threadIdx.x;
    const int w    = tid >> 6;
    const int lane = tid & 63;
    const int wm   = w % 2;
    const int wn   = w / 2;
    const int rowbase = arow0 + wm * 64 + (lane >> 4) * 4;
    const int colbase = wn * 64 + (lane & 15);
#pragma unroll
    for (int ni = 0; ni < 4; ++ni) {
        const int col = colbase + ni * 16;
        const float bv = b1[col];
#pragma unroll
        for (int mi = 0; mi < 4; ++mi)
#pragma unroll
            for (int reg = 0; reg < 4; ++reg) {
                const int row = rowbase + mi * 16 + reg;
                float v = acc[mi][ni][reg] + bv;
                v = (v > 0.f) ? v : expm1f(v);
                Hbf[(size_t)row * 256 + col] = f2bf(v);
            }
    }
}

// ---------------------------------------------------------------------------
// proj2 + normalize fused -> zn bf16 in [b][set][l][256] order.
// ---------------------------------------------------------------------------
__global__ __launch_bounds__(512) void proj2norm_kernel(
    const short* __restrict__ Hbf, const short* __restrict__ W2bf,
    const float* __restrict__ b2, short* __restrict__ zn)
{
    __shared__ short lsA[8192];
    __shared__ short lsB[16384];
    __shared__ float rssq[4][128];
    __shared__ float rinv[128];
    const int arow0 = blockIdx.x * 128;
    float4v acc[4][4];
#pragma unroll
    for (int mi = 0; mi < 4; ++mi)
#pragma unroll
        for (int ni = 0; ni < 4; ++ni)
            acc[mi][ni] = (float4v){0.f, 0.f, 0.f, 0.f};

    gemm512_core<128, 256, 2>(Hbf, W2bf, arow0, 0, lsA, lsB, acc);

    const int tid  = threadIdx.x;
    const int w    = tid >> 6;
    const int lane = tid & 63;
    const int wm   = w % 2;
    const int wn   = w / 2;

#pragma unroll
    for (int ni = 0; ni < 4; ++ni) {
        const float bv = b2[wn * 64 + ni * 16 + (lane & 15)];
#pragma unroll
        for (int mi = 0; mi < 4; ++mi)
#pragma unroll
            for (int reg = 0; reg < 4; ++reg)
                acc[mi][ni][reg] += bv;
    }
    float ps[4][4];
#pragma unroll
    for (int mi = 0; mi < 4; ++mi)
#pragma unroll
        for (int reg = 0; reg < 4; ++reg) {
            float s = 0.f;
#pragma unroll
            for (int ni = 0; ni < 4; ++ni) {
                float v = acc[mi][ni][reg];
                s += v * v;
            }
            s += __shfl_xor(s, 1); s += __shfl_xor(s, 2);
            s += __shfl_xor(s, 4); s += __shfl_xor(s, 8);
            ps[mi][reg] = s;
        }
    if ((lane & 15) == 0) {
        const int g = lane >> 4;
#pragma unroll
        for (int mi = 0; mi < 4; ++mi)
#pragma unroll
            for (int reg = 0; reg < 4; ++reg)
                rssq[wn][wm * 64 + mi * 16 + g * 4 + reg] = ps[mi][reg];
    }
    __syncthreads();
    if (tid < 128) {
        float ssq = rssq[0][tid] + rssq[1][tid] + rssq[2][tid] + rssq[3][tid];
        rinv[tid] = 1.0f / fmaxf(sqrtf(ssq), 1e-12f);
    }
    __syncthreads();

    const int r0  = arow0;
    const int set = r0 >> 14;
    const int bb  = (r0 >> 12) & 3;
    const int l0  = r0 & 4095;
    short* dst = zn + ((size_t)(bb * 2 + set) * 4096 + l0) * 256;
    const int colbase = wn * 64 + (lane & 15);
#pragma unroll
    for (int mi = 0; mi < 4; ++mi)
#pragma unroll
        for (int reg = 0; reg < 4; ++reg) {
            const int rl = wm * 64 + mi * 16 + (lane >> 4) * 4 + reg;
            const float inv = rinv[rl];
#pragma unroll
            for (int ni = 0; ni < 4; ++ni)
                dst[(size_t)rl * 256 + colbase + ni * 16] =
                    f2bf(acc[mi][ni][reg] * inv);
        }
}

// ---------------------------------------------------------------------------
// Flash-gram R7: grid 512 blocks x 512 threads.  Block = (batch, stripe of
// 128 q-rows, half of j-range).  A-stripe in LDS (staged once); B frags
// stream global->VGPR, 4-slot rotating prefetch 3 steps ahead; no barriers
// in the hot loop.  Wave grid 2 wm x 4 wn (64 rows x 32 cols each).
// Rowsum partials -> atomicAdd into S[batch*8192+q]; d-term (block owning
// the diag tile) -> atomicAdd(out, -0.25*dsum) [0.125 * -2 * dsum].
// ---------------------------------------------------------------------------
__global__ __launch_bounds__(512, 4) void gram_flash_kernel(
    const short* __restrict__ zn, float* __restrict__ S,
    float* __restrict__ out)
{
    __shared__ short lsA[32768];      // [kseg 0..31][row 0..127][8 bf16]
    __shared__ float smS[4][128];     // [wn][row] rowsum partials
    __shared__ float redd[8];         // per-wave dsum

    const int bx    = blockIdx.x;             // 0..511
    const int xcd   = bx & 7;                 // batch -> XCD pair {2b,2b+1}
    const int batch = xcd >> 1;
    const int id    = (bx >> 3) * 2 + (xcd & 1);    // 0..127
    const int stripe = id >> 1;               // 0..63
    const int half   = id & 1;                // j-range half
    const short* Z = zn + (size_t)batch * (8192 * 256);
    const int q0 = stripe * 128;
    const int j0 = half * 32;
    const int dj = ((stripe < 32) ? (stripe + 32) : (stripe - 32)) - j0;

    const int tid  = threadIdx.x;
    const int w    = tid >> 6;
    const int lane = tid & 63;
    const int wm   = w & 1;        // m-half (64 rows)
    const int wn   = w >> 1;       // n-quarter (32 cols)
    const int quad = lane >> 4;
    const int l15  = lane & 15;

    // ---- stage A-stripe into LDS once (fragment-contiguous [kseg][row][8])
#pragma unroll
    for (int r = 0; r < 8; ++r) {
        const int c    = w * 8 + r;           // 0..63 chunks
        const int kseg = c >> 1;
        const int nb   = (c & 1) * 64;
        gl_lds16(Z + (size_t)(q0 + nb + lane) * 256 + kseg * 8,
                 lsA + (size_t)c * 512);
    }

    // ---- B streaming pointers (tiles j0 .. j0+31):
    const short* Bp0 = Z + (size_t)(j0 * 128 + wn * 32 + l15) * 256 + quad * 8;
    const short* Bp1 = Bp0 + 16 * 256;

    short8 bb[4][2];                  // rotating, slot = step & 3
#pragma unroll
    for (int p = 0; p < 3; ++p) {     // preload steps 0,1,2
        bb[p][0] = *(const short8*)(Bp0 + p * 32);
        bb[p][1] = *(const short8*)(Bp1 + p * 32);
    }

    float rs[4][4];
#pragma unroll
    for (int mi = 0; mi < 4; ++mi)
#pragma unroll
        for (int reg = 0; reg < 4; ++reg)
            rs[mi][reg] = 0.f;
    float dsum = 0.f;

    __syncthreads();                  // A-stage complete (drains vmcnt)

    const float C2L = 2.8853900817779268f;    // 2/ln(2): exp(2x)=exp2(x*C2L)

    for (int j = 0; j < 32; ++j) {
        float4v acc[4][2];
#pragma unroll
        for (int mi = 0; mi < 4; ++mi) {
            acc[mi][0] = (float4v){0.f, 0.f, 0.f, 0.f};
            acc[mi][1] = (float4v){0.f, 0.f, 0.f, 0.f};
        }
        const size_t jb = (size_t)j * 32768;
#pragma unroll
        for (int kc = 0; kc < 8; ++kc) {
            // prefetch step 8j+kc+3 into slot (kc+3)&3 (compile-time)
            const int   slot = (kc + 3) & 3;
            const size_t off = jb + (size_t)((kc + 3) >> 3) * 32768
                                  + (size_t)((kc + 3) & 7) * 32;
            bb[slot][0] = *(const short8*)(Bp0 + off);
            bb[slot][1] = *(const short8*)(Bp1 + off);
            // A frags from LDS, B from regs (slot kc&3)
            const int cs   = kc & 3;
            const int kseg = kc * 4 + quad;
#pragma unroll
            for (int mi = 0; mi < 4; ++mi) {
                short8 af = *(const short8*)(lsA +
                    ((size_t)kseg * 128 + wm * 64 + mi * 16 + l15) * 8);
                acc[mi][0] = __builtin_amdgcn_mfma_f32_16x16x32_bf16(
                    af, bb[cs][0], acc[mi][0], 0, 0, 0);
                acc[mi][1] = __builtin_amdgcn_mfma_f32_16x16x32_bf16(
                    af, bb[cs][1], acc[mi][1], 0, 0, 0);
            }
        }

        if (j == dj) {   // raw z1.z2 diagonal of the cross tile
#pragma unroll
            for (int mi = 0; mi < 4; ++mi)
#pragma unroll
                for (int ni = 0; ni < 2; ++ni)
#pragma unroll
                    for (int reg = 0; reg < 4; ++reg) {
                        const int row = wm * 64 + mi * 16 + quad * 4 + reg;
                        const int col = wn * 32 + ni * 16 + l15;
                        if (row == col) dsum += acc[mi][ni][reg];
                    }
        }

#pragma unroll
        for (int mi = 0; mi < 4; ++mi)
#pragma unroll
            for (int reg = 0; reg < 4; ++reg)
                rs[mi][reg] += exp2f(acc[mi][0][reg] * C2L)
                             + exp2f(acc[mi][1][reg] * C2L);
    }

    // ---- epilogue: combine the 4 wn-wave 32-col partials per row in LDS,
    // then atomicAdd partial rowsums into S (log happens in final kernel).
#pragma unroll
    for (int mi = 0; mi < 4; ++mi)
#pragma unroll
        for (int reg = 0; reg < 4; ++reg) {
            float v = rs[mi][reg];
            v += __shfl_xor(v, 1); v += __shfl_xor(v, 2);
            v += __shfl_xor(v, 4); v += __shfl_xor(v, 8);
            rs[mi][reg] = v;
        }
    __syncthreads();                  // lsA reads done; reuse LDS for smS
    if (l15 == 0) {
#pragma unroll
        for (int mi = 0; mi < 4; ++mi)
#pragma unroll
            for (int reg = 0; reg < 4; ++reg)
                smS[wn][wm * 64 + mi * 16 + quad * 4 + reg] = rs[mi][reg];
    }
    {
        float dv = dsum;
        dv += __shfl_xor(dv, 1);  dv += __shfl_xor(dv, 2);
        dv += __shfl_xor(dv, 4);  dv += __shfl_xor(dv, 8);
        dv += __shfl_xor(dv, 16); dv += __shfl_xor(dv, 32);
        if (lane == 0) redd[w] = dv;
    }
    __syncthreads();

    if (tid < 128)
        atomicAdd(&S[(size_t)batch * 8192 + q0 + tid],
                  smS[0][tid] + smS[1][tid] + smS[2][tid] + smS[3][tid]);
    if (tid == 0) {
        float d = redd[0] + redd[1] + redd[2] + redd[3]
                + redd[4] + redd[5] + redd[6] + redd[7];
        if (d != 0.f) atomicAdd(out, -0.25f * d);   // 0.125 * (-2) * dsum
    }
}

// ---------------------------------------------------------------------------
// final: out += 0.125 * sum_{32768} log(S - e^2)
// ---------------------------------------------------------------------------
__global__ __launch_bounds__(256) void final_log_kernel(
    const float* __restrict__ S, float* __restrict__ out)
{
    __shared__ float red[4];
    const int tid  = threadIdx.x;
    const int w    = tid >> 6;
    const int lane = tid & 63;
    const float E2 = 7.3890560989306495f;
    float acc = 0.f;
    for (int i = blockIdx.x * 256 + tid; i < 32768; i += gridDim.x * 256)
        acc += logf(S[i] - E2);
    acc += __shfl_xor(acc, 1);  acc += __shfl_xor(acc, 2);
    acc += __shfl_xor(acc, 4);  acc += __shfl_xor(acc, 8);
    acc += __shfl_xor(acc, 16); acc += __shfl_xor(acc, 32);
    if (lane == 0) red[w] = acc;
    __syncthreads();
    if (tid == 0)
        atomicAdd(out, 0.125f * (red[0] + red[1] + red[2] + red[3]));
}

// ---------------------------------------------------------------------------
// Workspace (bytes), total ~34 MB:
//   [0,       131072)  S (4*8192 fp32) | W1bf/W2bf packed after
//   [131072,  262144)  W1bf
//   [262144,  393216)  W2bf
//   [393216, 17170432) Xbf / zn (aliased; Xbf dead after proj1)
//   [17170432,33947648) Hbf  (also absorbs gram's tile-64 prefetch overread)
// ---------------------------------------------------------------------------
extern "C" void kernel_launch(void* const* d_in, const int* in_sizes, int n_in,
                              void* d_out, int out_size, void* d_ws, size_t ws_size,
                              hipStream_t stream)
{
    const float* X1 = (const float*)d_in[0];
    const float* X2 = (const float*)d_in[1];
    const float* W1 = (const float*)d_in[2];
    const float* b1 = (const float*)d_in[3];
    const float* W2 = (const float*)d_in[4];
    const float* b2 = (const float*)d_in[5];

    char* ws = (char*)d_ws;
    float* S    = (float*)(ws + 0);
    short* W1bf = (short*)(ws + 131072);
    short* W2bf = (short*)(ws + 262144);
    short* Xbf  = (short*)(ws + 393216);
    short* zn   = (short*)(ws + 393216);
    short* Hbf  = (short*)(ws + 17170432);

    hipMemsetAsync(S, 0, 131072, stream);
    hipMemsetAsync(d_out, 0, sizeof(float), stream);

    convW_kernel<<<128, 256, 0, stream>>>(W1, W2, W1bf, W2bf);
    convX_kernel<<<8192, 256, 0, stream>>>(X1, X2, Xbf);
    proj1_kernel<<<256, 512, 0, stream>>>(Xbf, W1bf, b1, Hbf);
    proj2norm_kernel<<<256, 512, 0, stream>>>(Hbf, W2bf, b2, zn);
    gram_flash_kernel<<<512, 512, 0, stream>>>(zn, S, (float*)d_out);
    final_log_kernel<<<64, 256, 0, stream>>>(S, (float*)d_out);
}

// Round 8
// 595.123 us; speedup vs baseline: 1.1889x; 1.1889x over previous
//
#include <hip/hip_runtime.h>
#include <math.h>

// ---------------------------------------------------------------------------
// Problem: B=4, L=4096, D=P=256, tau=0.5
// out = (1/8) * sum_{b,l} [ log(S1-e^2) + log(S2-e^2) - 4*d[b,l] ]
//   S[b,q] = sum_{m<2L} exp(2 * Zhat[b,q].Zhat[b,m]),  Zhat = [z1n; z2n]
// R8: Gram in FP8 e4m3 (MFMA at bf16 rate, half the bytes/regs).  256-thread
// blocks, 4 waves, ZERO LDS, zero in-loop barriers: A-stripe (32 rows/wave)
// in 32 VGPRs, B streamed global->VGPR with 4-slot rotating prefetch.
// ~100 regs total -> 4 blocks/CU (R7 lesson: 512,4 + 160 regs = scratch
// spill disaster, FETCH 1.5 GB).  Batch pinned to XCD pair: 2.1 MB fp8 Z
// is L2-resident.  Rowsum partials -> S atomics; log in final kernel.
// ---------------------------------------------------------------------------

typedef __attribute__((ext_vector_type(8))) short short8;
typedef __attribute__((ext_vector_type(4))) short short4v;
typedef __attribute__((ext_vector_type(4))) float float4v;

__device__ __forceinline__ short f2bf(float f) {
    unsigned u = __builtin_bit_cast(unsigned, f);
    u += 0x7fffu + ((u >> 16) & 1u);          // RNE
    return (short)(u >> 16);
}

// manual fp32 -> fp8 e4m3fn (OCP), RNE.  |f| <= ~1.1 here (normalized z).
__device__ __forceinline__ unsigned char f2fp8(float f) {
    float af = fabsf(f);
    unsigned s = (__builtin_bit_cast(unsigned, f) >> 31) << 7;
    if (af < 0.015625f) {                     // subnormal (<2^-6); 8 rolls up
        int q = (int)rintf(af * 512.0f);
        return (unsigned char)(s | (unsigned)q);
    }
    unsigned au = __builtin_bit_cast(unsigned, af);
    au += 0x7FFFFu + ((au >> 20) & 1u);       // RNE at bit 20
    int e = (int)(au >> 23) - 127;
    unsigned m = (au >> 20) & 7u;
    return (unsigned char)(s | (unsigned)((e + 7) << 3) | m);
}

__device__ __forceinline__ void gl_lds16(const short* g, short* l) {
    __builtin_amdgcn_global_load_lds(
        (const __attribute__((address_space(1))) void*)g,
        (__attribute__((address_space(3))) void*)l, 16, 0, 0);
}

// ---------------------------------------------------------------------------
// 512-thread NT-GEMM core (verified R2/R3): C[RAxRB] = A*B^T, K=256, bf16.
// ---------------------------------------------------------------------------
template <int RA, int RB, int NWM>
__device__ __forceinline__ void gemm512_core(
    const short* __restrict__ A, const short* __restrict__ B,
    int arow0, int brow0, short* lsA, short* lsB, float4v acc[4][4])
{
    const int tid  = threadIdx.x;
    const int w    = tid >> 6;
    const int lane = tid & 63;
    const int wm   = w % NWM;
    const int wn   = w / NWM;
    constexpr int ACH = RA / 8;

    for (int kt = 0; kt < 4; ++kt) {
        const int kbase = kt * 64;
#pragma unroll
        for (int r = 0; r < 6; ++r) {
            const int c = w * 6 + r;
            if (c < ACH) {
                const int s   = c * 64 + lane;
                const int kc  = s / RA;
                const int row = s % RA;
                gl_lds16(A + (size_t)(arow0 + row) * 256 + kbase + kc * 8,
                         lsA + (size_t)c * 512);
            } else {
                const int s   = (c - ACH) * 64 + lane;
                const int kc  = s / RB;
                const int row = s % RB;
                gl_lds16(B + (size_t)(brow0 + row) * 256 + kbase + kc * 8,
                         lsB + (size_t)(c - ACH) * 512);
            }
        }
        __syncthreads();
#pragma unroll
        for (int ks = 0; ks < 2; ++ks) {
            const int kc = ks * 4 + (lane >> 4);
            short8 af[4], bfv[4];
#pragma unroll
            for (int mi = 0; mi < 4; ++mi)
                af[mi] = *(const short8*)(lsA + ((size_t)kc * RA + wm * 64 + mi * 16 + (lane & 15)) * 8);
#pragma unroll
            for (int ni = 0; ni < 4; ++ni)
                bfv[ni] = *(const short8*)(lsB + ((size_t)kc * RB + wn * 64 + ni * 16 + (lane & 15)) * 8);
#pragma unroll
            for (int mi = 0; mi < 4; ++mi)
#pragma unroll
                for (int ni = 0; ni < 4; ++ni)
                    acc[mi][ni] = __builtin_amdgcn_mfma_f32_16x16x32_bf16(
                        af[mi], bfv[ni], acc[mi][ni], 0, 0, 0);
        }
        __syncthreads();
    }
}

// ---------------------------------------------------------------------------
// fp32 -> bf16 converters
// ---------------------------------------------------------------------------
__global__ __launch_bounds__(256) void convX_kernel(
    const float* __restrict__ X1, const float* __restrict__ X2,
    short* __restrict__ dst)
{
    int i = blockIdx.x * 256 + threadIdx.x;
    const float* src = (i < 1048576) ? X1 : X2;
    int j = i & 1048575;
    float4v v = ((const float4v*)src)[j];
    short4v o;
    o.x = f2bf(v.x); o.y = f2bf(v.y); o.z = f2bf(v.z); o.w = f2bf(v.w);
    ((short4v*)dst)[i] = o;
}

__global__ __launch_bounds__(256) void convW_kernel(
    const float* __restrict__ W1, const float* __restrict__ W2,
    short* __restrict__ d1, short* __restrict__ d2)
{
    int i = blockIdx.x * 256 + threadIdx.x;
    const float* src = (i < 16384) ? W1 : W2;
    short* dst = (i < 16384) ? d1 : d2;
    int j = i & 16383;
    float4v v = ((const float4v*)src)[j];
    short4v o;
    o.x = f2bf(v.x); o.y = f2bf(v.y); o.z = f2bf(v.z); o.w = f2bf(v.w);
    ((short4v*)dst)[j] = o;
}

// ---------------------------------------------------------------------------
// proj1: H = elu(X*W1^T + b1) bf16, 32768x256, grid 256 x 512thr.
// ---------------------------------------------------------------------------
__global__ __launch_bounds__(512) void proj1_kernel(
    const short* __restrict__ Xbf, const short* __restrict__ W1bf,
    const float* __restrict__ b1, short* __restrict__ Hbf)
{
    __shared__ short lsA[8192];
    __shared__ short lsB[16384];
    const int arow0 = blockIdx.x * 128;
    float4v acc[4][4];
#pragma unroll
    for (int mi = 0; mi < 4; ++mi)
#pragma unroll
        for (int ni = 0; ni < 4; ++ni)
            acc[mi][ni] = (float4v){0.f, 0.f, 0.f, 0.f};

    gemm512_core<128, 256, 2>(Xbf, W1bf, arow0, 0, lsA, lsB, acc);

    const int tid  = threadIdx.x;
    const int w    = tid >> 6;
    const int lane = tid & 63;
    const int wm   = w % 2;
    const int wn   = w / 2;
    const int rowbase = arow0 + wm * 64 + (lane >> 4) * 4;
    const int colbase = wn * 64 + (lane & 15);
#pragma unroll
    for (int ni = 0; ni < 4; ++ni) {
        const int col = colbase + ni * 16;
        const float bv = b1[col];
#pragma unroll
        for (int mi = 0; mi < 4; ++mi)
#pragma unroll
            for (int reg = 0; reg < 4; ++reg) {
                const int row = rowbase + mi * 16 + reg;
                float v = acc[mi][ni][reg] + bv;
                v = (v > 0.f) ? v : expm1f(v);
                Hbf[(size_t)row * 256 + col] = f2bf(v);
            }
    }
}

// ---------------------------------------------------------------------------
// proj2 + normalize fused -> zn FP8 e4m3 in [b][set][l][256] byte order.
// ---------------------------------------------------------------------------
__global__ __launch_bounds__(512) void proj2norm_kernel(
    const short* __restrict__ Hbf, const short* __restrict__ W2bf,
    const float* __restrict__ b2, unsigned char* __restrict__ zn8)
{
    __shared__ short lsA[8192];
    __shared__ short lsB[16384];
    __shared__ float rssq[4][128];
    __shared__ float rinv[128];
    const int arow0 = blockIdx.x * 128;
    float4v acc[4][4];
#pragma unroll
    for (int mi = 0; mi < 4; ++mi)
#pragma unroll
        for (int ni = 0; ni < 4; ++ni)
            acc[mi][ni] = (float4v){0.f, 0.f, 0.f, 0.f};

    gemm512_core<128, 256, 2>(Hbf, W2bf, arow0, 0, lsA, lsB, acc);

    const int tid  = threadIdx.x;
    const int w    = tid >> 6;
    const int lane = tid & 63;
    const int wm   = w % 2;
    const int wn   = w / 2;

#pragma unroll
    for (int ni = 0; ni < 4; ++ni) {
        const float bv = b2[wn * 64 + ni * 16 + (lane & 15)];
#pragma unroll
        for (int mi = 0; mi < 4; ++mi)
#pragma unroll
            for (int reg = 0; reg < 4; ++reg)
                acc[mi][ni][reg] += bv;
    }
    float ps[4][4];
#pragma unroll
    for (int mi = 0; mi < 4; ++mi)
#pragma unroll
        for (int reg = 0; reg < 4; ++reg) {
            float s = 0.f;
#pragma unroll
            for (int ni = 0; ni < 4; ++ni) {
                float v = acc[mi][ni][reg];
                s += v * v;
            }
            s += __shfl_xor(s, 1); s += __shfl_xor(s, 2);
            s += __shfl_xor(s, 4); s += __shfl_xor(s, 8);
            ps[mi][reg] = s;
        }
    if ((lane & 15) == 0) {
        const int g = lane >> 4;
#pragma unroll
        for (int mi = 0; mi < 4; ++mi)
#pragma unroll
            for (int reg = 0; reg < 4; ++reg)
                rssq[wn][wm * 64 + mi * 16 + g * 4 + reg] = ps[mi][reg];
    }
    __syncthreads();
    if (tid < 128) {
        float ssq = rssq[0][tid] + rssq[1][tid] + rssq[2][tid] + rssq[3][tid];
        rinv[tid] = 1.0f / fmaxf(sqrtf(ssq), 1e-12f);
    }
    __syncthreads();

    const int r0  = arow0;
    const int set = r0 >> 14;
    const int bb  = (r0 >> 12) & 3;
    const int l0  = r0 & 4095;
    unsigned char* dst = zn8 + ((size_t)(bb * 2 + set) * 4096 + l0) * 256;
    const int colbase = wn * 64 + (lane & 15);
#pragma unroll
    for (int mi = 0; mi < 4; ++mi)
#pragma unroll
        for (int reg = 0; reg < 4; ++reg) {
            const int rl = wm * 64 + mi * 16 + (lane >> 4) * 4 + reg;
            const float inv = rinv[rl];
#pragma unroll
            for (int ni = 0; ni < 4; ++ni)
                dst[(size_t)rl * 256 + colbase + ni * 16] =
                    f2fp8(acc[mi][ni][reg] * inv);
        }
}

// ---------------------------------------------------------------------------
// FP8 flash-gram: grid 1024 blocks x 256 threads (4 waves), zero LDS.
// Block = (batch, 128-row q-stripe, quarter of j-range [slice*32,+32) tiles
// of 64 cols).  Wave = 32 rows x 64 cols; A-frags afr[2][8] in 32 VGPRs;
// B-frags bb[4 slots][4] streamed global->VGPR, prefetch 3 kc-steps ahead.
// mfma_f32_16x16x32_fp8_fp8 (i64 operands, bf16 rate).  Per-row partial
// rowsums of exp(2 dot) -> atomicAdd S; diag of cross tile -> d-term.
// Overread: last 3 prefetches touch up to ~16KB past the slice (in-bounds:
// zn8 is followed by Xbf slack in the workspace).
// ---------------------------------------------------------------------------
__global__ __launch_bounds__(256, 4) void gram_fp8_kernel(
    const unsigned char* __restrict__ zn8, float* __restrict__ S,
    float* __restrict__ out)
{
    const int bx    = blockIdx.x;             // 0..1023
    const int xcd   = bx & 7;                 // batch -> XCD pair {2b,2b+1}
    const int batch = xcd >> 1;
    const int sub   = (bx >> 3) * 2 + (bx & 1);     // 0..255
    const int stripe = sub & 63;              // 128-row q-stripe
    const int slice  = sub >> 6;              // j-range quarter (32 tiles)
    const unsigned char* Z  = zn8 + (size_t)batch * 2097152;
    const unsigned char* Zb = Z + (size_t)slice * 524288;   // slice base
    const int q0 = stripe * 128;

    const int tid  = threadIdx.x;
    const int w    = tid >> 6;                // wm 0..3 (32-row band)
    const int lane = tid & 63;
    const int quad = lane >> 4;
    const int l15  = lane & 15;

    // partner-diagonal tiles (cols [q0^4096, +128) = two 64-col tiles)
    const int djt0 = (q0 ^ 4096) >> 6;

    // ---- A fragments (fp8): 8 contiguous bytes per (mi,kc)
    long afr[2][8];
    {
        const unsigned char* Ab = Z + (size_t)(q0 + w * 32) * 256;
#pragma unroll
        for (int mi = 0; mi < 2; ++mi)
#pragma unroll
            for (int kc = 0; kc < 8; ++kc)
                afr[mi][kc] = *(const long*)(Ab + (size_t)(mi * 16 + l15) * 256
                                             + kc * 32 + quad * 8);
    }

    // ---- B per-lane offsets (within slice): frag fi covers cols fi*16+l15
    int loff[4];
#pragma unroll
    for (int fi = 0; fi < 4; ++fi)
        loff[fi] = (fi * 16 + l15) * 256 + quad * 8;

    long bb[4][4];                    // [slot][frag], slot = kc-step & 3
#pragma unroll
    for (int p = 0; p < 3; ++p)       // preload steps (j=0, kc=0..2)
#pragma unroll
        for (int fi = 0; fi < 4; ++fi)
            bb[p][fi] = *(const long*)(Zb + p * 32 + loff[fi]);

    float rs[2][4];
#pragma unroll
    for (int mi = 0; mi < 2; ++mi)
#pragma unroll
        for (int reg = 0; reg < 4; ++reg)
            rs[mi][reg] = 0.f;
    float dsum = 0.f;

    const float C2L = 2.8853900817779268f;    // 2/ln2: exp(2x)=exp2(x*C2L)

    for (int j = 0; j < 32; ++j) {
        float4v acc[2][4];
#pragma unroll
        for (int mi = 0; mi < 2; ++mi)
#pragma unroll
            for (int ni = 0; ni < 4; ++ni)
                acc[mi][ni] = (float4v){0.f, 0.f, 0.f, 0.f};

        const int jb = j * 16384;             // 64 rows * 256 B
#pragma unroll
        for (int kc = 0; kc < 8; ++kc) {
            // prefetch step 8j+kc+3 -> slot (kc+3)&3 (compile-time indices)
            const int slot = (kc + 3) & 3;
            const int off  = jb + ((kc + 3) >> 3) * 16384 + ((kc + 3) & 7) * 32;
#pragma unroll
            for (int fi = 0; fi < 4; ++fi)
                bb[slot][fi] = *(const long*)(Zb + off + loff[fi]);
            const int cs = kc & 3;
#pragma unroll
            for (int mi = 0; mi < 2; ++mi)
#pragma unroll
                for (int ni = 0; ni < 4; ++ni)
                    acc[mi][ni] = __builtin_amdgcn_mfma_f32_16x16x32_fp8_fp8(
                        afr[mi][kc], bb[cs][ni], acc[mi][ni], 0, 0, 0);
        }

        const int jabs = slice * 32 + j;
        if (jabs == djt0 || jabs == djt0 + 1) {   // cross-diagonal tile
#pragma unroll
            for (int mi = 0; mi < 2; ++mi)
#pragma unroll
                for (int ni = 0; ni < 4; ++ni)
#pragma unroll
                    for (int reg = 0; reg < 4; ++reg) {
                        const int rg = q0 + w * 32 + mi * 16 + quad * 4 + reg;
                        const int cg = jabs * 64 + ni * 16 + l15;
                        if ((rg ^ 4096) == cg) dsum += acc[mi][ni][reg];
                    }
        }

#pragma unroll
        for (int mi = 0; mi < 2; ++mi)
#pragma unroll
            for (int reg = 0; reg < 4; ++reg) {
                float s = 0.f;
#pragma unroll
                for (int ni = 0; ni < 4; ++ni)
                    s += exp2f(acc[mi][ni][reg] * C2L);
                rs[mi][reg] += s;
            }
    }

    // ---- epilogue: reduce rowsums over the 16 col-lanes; atomics into S.
#pragma unroll
    for (int mi = 0; mi < 2; ++mi)
#pragma unroll
        for (int reg = 0; reg < 4; ++reg) {
            float v = rs[mi][reg];
            v += __shfl_xor(v, 1); v += __shfl_xor(v, 2);
            v += __shfl_xor(v, 4); v += __shfl_xor(v, 8);
            rs[mi][reg] = v;
        }
    if (l15 == 0) {
        float* Sq = S + (size_t)batch * 8192 + q0 + w * 32;
#pragma unroll
        for (int mi = 0; mi < 2; ++mi)
#pragma unroll
            for (int reg = 0; reg < 4; ++reg)
                atomicAdd(&Sq[mi * 16 + quad * 4 + reg], rs[mi][reg]);
    }
    // d-term: wave-reduce, one atomic from waves that touched the diagonal
    {
        float dv = dsum;
        dv += __shfl_xor(dv, 1);  dv += __shfl_xor(dv, 2);
        dv += __shfl_xor(dv, 4);  dv += __shfl_xor(dv, 8);
        dv += __shfl_xor(dv, 16); dv += __shfl_xor(dv, 32);
        if (lane == 0 && dv != 0.f)
            atomicAdd(out, -0.25f * dv);      // 0.125 * (-2) * dsum
    }
}

// ---------------------------------------------------------------------------
// final: out += 0.125 * sum_{32768} log(S - e^2)
// ---------------------------------------------------------------------------
__global__ __launch_bounds__(256) void final_log_kernel(
    const float* __restrict__ S, float* __restrict__ out)
{
    __shared__ float red[4];
    const int tid  = threadIdx.x;
    const int w    = tid >> 6;
    const int lane = tid & 63;
    const float E2 = 7.3890560989306495f;
    float acc = 0.f;
    for (int i = blockIdx.x * 256 + tid; i < 32768; i += gridDim.x * 256)
        acc += logf(S[i] - E2);
    acc += __shfl_xor(acc, 1);  acc += __shfl_xor(acc, 2);
    acc += __shfl_xor(acc, 4);  acc += __shfl_xor(acc, 8);
    acc += __shfl_xor(acc, 16); acc += __shfl_xor(acc, 32);
    if (lane == 0) red[w] = acc;
    __syncthreads();
    if (tid == 0)
        atomicAdd(out, 0.125f * (red[0] + red[1] + red[2] + red[3]));
}

// ---------------------------------------------------------------------------
// Workspace (bytes), total ~34 MB:
//   [0,       131072)  S (4*8192 fp32)
//   [131072,  262144)  W1bf
//   [262144,  393216)  W2bf
//   [393216, 17170432) Xbf (bf16, 16.7MB) / zn8 (fp8, first 8.4MB; aliased —
//                      Xbf dead after proj1; zn8 overread slack follows)
//   [17170432,33947648) Hbf
// ---------------------------------------------------------------------------
extern "C" void kernel_launch(void* const* d_in, const int* in_sizes, int n_in,
                              void* d_out, int out_size, void* d_ws, size_t ws_size,
                              hipStream_t stream)
{
    const float* X1 = (const float*)d_in[0];
    const float* X2 = (const float*)d_in[1];
    const float* W1 = (const float*)d_in[2];
    const float* b1 = (const float*)d_in[3];
    const float* W2 = (const float*)d_in[4];
    const float* b2 = (const float*)d_in[5];

    char* ws = (char*)d_ws;
    float* S    = (float*)(ws + 0);
    short* W1bf = (short*)(ws + 131072);
    short* W2bf = (short*)(ws + 262144);
    short* Xbf  = (short*)(ws + 393216);
    unsigned char* zn8 = (unsigned char*)(ws + 393216);
    short* Hbf  = (short*)(ws + 17170432);

    hipMemsetAsync(S, 0, 131072, stream);
    hipMemsetAsync(d_out, 0, sizeof(float), stream);

    convW_kernel<<<128, 256, 0, stream>>>(W1, W2, W1bf, W2bf);
    convX_kernel<<<8192, 256, 0, stream>>>(X1, X2, Xbf);
    proj1_kernel<<<256, 512, 0, stream>>>(Xbf, W1bf, b1, Hbf);
    proj2norm_kernel<<<256, 512, 0, stream>>>(Hbf, W2bf, b2, zn8);
    gram_fp8_kernel<<<1024, 256, 0, stream>>>(zn8, S, (float*)d_out);
    final_log_kernel<<<64, 256, 0, stream>>>(S, (float*)d_out);
}

// Round 9
// 252.107 us; speedup vs baseline: 2.8064x; 2.3606x over previous
//
#include <hip/hip_runtime.h>
#include <math.h>

// ---------------------------------------------------------------------------
// Problem: B=4, L=4096, D=P=256, tau=0.5
// out = (1/8) * sum_{b,l} [ log(S1-e^2) + log(S2-e^2) - 4*d[b,l] ]
//   S[b,q] = sum_{m<2L} exp(2 * Zhat[b,q].Zhat[b,m]),  Zhat = [z1n; z2n]
// R9 gram: R5's verified LDS-dbuf flash structure, fp8 operands (R8-verified
// numerics), 2 blocks/CU.  Anchor: gram_time = 57us / MfmaUtil (dense floor
// 137 GFLOP @ 2.4PF).  R5 = 24.7% util at 1 block/CU; doubling resident
// blocks overlaps the per-iter barrier drain -> target ~50%.
// Wave = 32 rows x 64 cols (wave grid 4 wm x 2 wn); A-stripe in 32 VGPRs;
// B j-tile (128 cols x 256B fp8 = 32 KB) double-buffered in LDS via
// global_load_lds(16B); ONE barrier per iter (drains the prefetch).
// ---------------------------------------------------------------------------

typedef __attribute__((ext_vector_type(8))) short short8;
typedef __attribute__((ext_vector_type(4))) short short4v;
typedef __attribute__((ext_vector_type(4))) float float4v;

__device__ __forceinline__ short f2bf(float f) {
    unsigned u = __builtin_bit_cast(unsigned, f);
    u += 0x7fffu + ((u >> 16) & 1u);          // RNE
    return (short)(u >> 16);
}

// manual fp32 -> fp8 e4m3fn (OCP), RNE.  |f| <= ~1.1 here (normalized z).
__device__ __forceinline__ unsigned char f2fp8(float f) {
    float af = fabsf(f);
    unsigned s = (__builtin_bit_cast(unsigned, f) >> 31) << 7;
    if (af < 0.015625f) {                     // subnormal (<2^-6); 8 rolls up
        int q = (int)rintf(af * 512.0f);
        return (unsigned char)(s | (unsigned)q);
    }
    unsigned au = __builtin_bit_cast(unsigned, af);
    au += 0x7FFFFu + ((au >> 20) & 1u);       // RNE at bit 20
    int e = (int)(au >> 23) - 127;
    unsigned m = (au >> 20) & 7u;
    return (unsigned char)(s | (unsigned)((e + 7) << 3) | m);
}

__device__ __forceinline__ void gl_lds16(const void* g, void* l) {
    __builtin_amdgcn_global_load_lds(
        (const __attribute__((address_space(1))) void*)g,
        (__attribute__((address_space(3))) void*)l, 16, 0, 0);
}

// ---------------------------------------------------------------------------
// 512-thread NT-GEMM core (verified R2/R3): C[RAxRB] = A*B^T, K=256, bf16.
// ---------------------------------------------------------------------------
template <int RA, int RB, int NWM>
__device__ __forceinline__ void gemm512_core(
    const short* __restrict__ A, const short* __restrict__ B,
    int arow0, int brow0, short* lsA, short* lsB, float4v acc[4][4])
{
    const int tid  = threadIdx.x;
    const int w    = tid >> 6;
    const int lane = tid & 63;
    const int wm   = w % NWM;
    const int wn   = w / NWM;
    constexpr int ACH = RA / 8;

    for (int kt = 0; kt < 4; ++kt) {
        const int kbase = kt * 64;
#pragma unroll
        for (int r = 0; r < 6; ++r) {
            const int c = w * 6 + r;
            if (c < ACH) {
                const int s   = c * 64 + lane;
                const int kc  = s / RA;
                const int row = s % RA;
                gl_lds16(A + (size_t)(arow0 + row) * 256 + kbase + kc * 8,
                         lsA + (size_t)c * 512);
            } else {
                const int s   = (c - ACH) * 64 + lane;
                const int kc  = s / RB;
                const int row = s % RB;
                gl_lds16(B + (size_t)(brow0 + row) * 256 + kbase + kc * 8,
                         lsB + (size_t)(c - ACH) * 512);
            }
        }
        __syncthreads();
#pragma unroll
        for (int ks = 0; ks < 2; ++ks) {
            const int kc = ks * 4 + (lane >> 4);
            short8 af[4], bfv[4];
#pragma unroll
            for (int mi = 0; mi < 4; ++mi)
                af[mi] = *(const short8*)(lsA + ((size_t)kc * RA + wm * 64 + mi * 16 + (lane & 15)) * 8);
#pragma unroll
            for (int ni = 0; ni < 4; ++ni)
                bfv[ni] = *(const short8*)(lsB + ((size_t)kc * RB + wn * 64 + ni * 16 + (lane & 15)) * 8);
#pragma unroll
            for (int mi = 0; mi < 4; ++mi)
#pragma unroll
                for (int ni = 0; ni < 4; ++ni)
                    acc[mi][ni] = __builtin_amdgcn_mfma_f32_16x16x32_bf16(
                        af[mi], bfv[ni], acc[mi][ni], 0, 0, 0);
        }
        __syncthreads();
    }
}

// ---------------------------------------------------------------------------
// fp32 -> bf16 converters
// ---------------------------------------------------------------------------
__global__ __launch_bounds__(256) void convX_kernel(
    const float* __restrict__ X1, const float* __restrict__ X2,
    short* __restrict__ dst)
{
    int i = blockIdx.x * 256 + threadIdx.x;
    const float* src = (i < 1048576) ? X1 : X2;
    int j = i & 1048575;
    float4v v = ((const float4v*)src)[j];
    short4v o;
    o.x = f2bf(v.x); o.y = f2bf(v.y); o.z = f2bf(v.z); o.w = f2bf(v.w);
    ((short4v*)dst)[i] = o;
}

__global__ __launch_bounds__(256) void convW_kernel(
    const float* __restrict__ W1, const float* __restrict__ W2,
    short* __restrict__ d1, short* __restrict__ d2)
{
    int i = blockIdx.x * 256 + threadIdx.x;
    const float* src = (i < 16384) ? W1 : W2;
    short* dst = (i < 16384) ? d1 : d2;
    int j = i & 16383;
    float4v v = ((const float4v*)src)[j];
    short4v o;
    o.x = f2bf(v.x); o.y = f2bf(v.y); o.z = f2bf(v.z); o.w = f2bf(v.w);
    ((short4v*)dst)[j] = o;
}

// ---------------------------------------------------------------------------
// proj1: H = elu(X*W1^T + b1) bf16, 32768x256, grid 256 x 512thr.
// ---------------------------------------------------------------------------
__global__ __launch_bounds__(512) void proj1_kernel(
    const short* __restrict__ Xbf, const short* __restrict__ W1bf,
    const float* __restrict__ b1, short* __restrict__ Hbf)
{
    __shared__ short lsA[8192];
    __shared__ short lsB[16384];
    const int arow0 = blockIdx.x * 128;
    float4v acc[4][4];
#pragma unroll
    for (int mi = 0; mi < 4; ++mi)
#pragma unroll
        for (int ni = 0; ni < 4; ++ni)
            acc[mi][ni] = (float4v){0.f, 0.f, 0.f, 0.f};

    gemm512_core<128, 256, 2>(Xbf, W1bf, arow0, 0, lsA, lsB, acc);

    const int tid  = threadIdx.x;
    const int w    = tid >> 6;
    const int lane = tid & 63;
    const int wm   = w % 2;
    const int wn   = w / 2;
    const int rowbase = arow0 + wm * 64 + (lane >> 4) * 4;
    const int colbase = wn * 64 + (lane & 15);
#pragma unroll
    for (int ni = 0; ni < 4; ++ni) {
        const int col = colbase + ni * 16;
        const float bv = b1[col];
#pragma unroll
        for (int mi = 0; mi < 4; ++mi)
#pragma unroll
            for (int reg = 0; reg < 4; ++reg) {
                const int row = rowbase + mi * 16 + reg;
                float v = acc[mi][ni][reg] + bv;
                v = (v > 0.f) ? v : expm1f(v);
                Hbf[(size_t)row * 256 + col] = f2bf(v);
            }
    }
}

// ---------------------------------------------------------------------------
// proj2 + normalize fused -> zn FP8 e4m3 in [b][set][l][256] byte order.
// ---------------------------------------------------------------------------
__global__ __launch_bounds__(512) void proj2norm_kernel(
    const short* __restrict__ Hbf, const short* __restrict__ W2bf,
    const float* __restrict__ b2, unsigned char* __restrict__ zn8)
{
    __shared__ short lsA[8192];
    __shared__ short lsB[16384];
    __shared__ float rssq[4][128];
    __shared__ float rinv[128];
    const int arow0 = blockIdx.x * 128;
    float4v acc[4][4];
#pragma unroll
    for (int mi = 0; mi < 4; ++mi)
#pragma unroll
        for (int ni = 0; ni < 4; ++ni)
            acc[mi][ni] = (float4v){0.f, 0.f, 0.f, 0.f};

    gemm512_core<128, 256, 2>(Hbf, W2bf, arow0, 0, lsA, lsB, acc);

    const int tid  = threadIdx.x;
    const int w    = tid >> 6;
    const int lane = tid & 63;
    const int wm   = w % 2;
    const int wn   = w / 2;

#pragma unroll
    for (int ni = 0; ni < 4; ++ni) {
        const float bv = b2[wn * 64 + ni * 16 + (lane & 15)];
#pragma unroll
        for (int mi = 0; mi < 4; ++mi)
#pragma unroll
            for (int reg = 0; reg < 4; ++reg)
                acc[mi][ni][reg] += bv;
    }
    float ps[4][4];
#pragma unroll
    for (int mi = 0; mi < 4; ++mi)
#pragma unroll
        for (int reg = 0; reg < 4; ++reg) {
            float s = 0.f;
#pragma unroll
            for (int ni = 0; ni < 4; ++ni) {
                float v = acc[mi][ni][reg];
                s += v * v;
            }
            s += __shfl_xor(s, 1); s += __shfl_xor(s, 2);
            s += __shfl_xor(s, 4); s += __shfl_xor(s, 8);
            ps[mi][reg] = s;
        }
    if ((lane & 15) == 0) {
        const int g = lane >> 4;
#pragma unroll
        for (int mi = 0; mi < 4; ++mi)
#pragma unroll
            for (int reg = 0; reg < 4; ++reg)
                rssq[wn][wm * 64 + mi * 16 + g * 4 + reg] = ps[mi][reg];
    }
    __syncthreads();
    if (tid < 128) {
        float ssq = rssq[0][tid] + rssq[1][tid] + rssq[2][tid] + rssq[3][tid];
        rinv[tid] = 1.0f / fmaxf(sqrtf(ssq), 1e-12f);
    }
    __syncthreads();

    const int r0  = arow0;
    const int set = r0 >> 14;
    const int bb  = (r0 >> 12) & 3;
    const int l0  = r0 & 4095;
    unsigned char* dst = zn8 + ((size_t)(bb * 2 + set) * 4096 + l0) * 256;
    const int colbase = wn * 64 + (lane & 15);
#pragma unroll
    for (int mi = 0; mi < 4; ++mi)
#pragma unroll
        for (int reg = 0; reg < 4; ++reg) {
            const int rl = wm * 64 + mi * 16 + (lane >> 4) * 4 + reg;
            const float inv = rinv[rl];
#pragma unroll
            for (int ni = 0; ni < 4; ++ni)
                dst[(size_t)rl * 256 + colbase + ni * 16] =
                    f2fp8(acc[mi][ni][reg] * inv);
        }
}

// ---------------------------------------------------------------------------
// FP8 flash-gram, LDS dbuf (R5 skeleton): grid 512 x 512thr (8 waves).
// Block = (batch, 128-row q-stripe, j-half of 32 tiles x 128 cols).
// Wave grid: wm = w&3 (32-row band), wn = w>>2 (64-col half).
// A-frags afr[2][8] in 32 VGPRs (8B fp8 frags).  B tile 32 KB in LDS,
// double-buffered; layout [kp 0..15][col 0..127][16B] so global_load_lds
// gets 16 contiguous global bytes (one col, 2 k-segments).
// Per iter: stage next tile (2048 x 16B, 4/thread), compute 64 MFMAs/wave,
// one __syncthreads (drains prefetch + guards buffer reuse).
// Rowsum partials -> atomicAdd S; diag of cross tile -> -2*dsum term.
// ---------------------------------------------------------------------------
__global__ __launch_bounds__(512, 2) void gram_fp8_kernel(
    const unsigned char* __restrict__ zn8, float* __restrict__ S,
    float* __restrict__ out)
{
    __shared__ unsigned char lsB[2][32768];   // [buf][kp][col][16]

    const int bx    = blockIdx.x;             // 0..511
    const int xcd   = bx & 7;                 // batch -> XCD pair {2b,2b+1}
    const int batch = xcd >> 1;
    const int sub   = (bx >> 3) * 2 + (xcd & 1);    // 0..127
    const int stripe = sub >> 1;              // 0..63: 128-row q-stripe
    const int half   = sub & 1;               // j-half
    const unsigned char* Z = zn8 + (size_t)batch * 2097152;
    const int q0 = stripe * 128;
    const int t0 = half * 32;                 // first 128-col j-tile
    const int djt = (q0 ^ 4096) >> 7;         // tile holding diagonal cols

    const int tid  = threadIdx.x;
    const int w    = tid >> 6;
    const int lane = tid & 63;
    const int wm   = w & 3;        // 32-row band
    const int wn   = w >> 2;       // 64-col half
    const int quad = lane >> 4;
    const int l15  = lane & 15;

    // ---- A fragments (fp8, 8B each): row q0+wm*32+mi*16+l15, k-bytes
    // kc*32+quad*8 (A[m=l15][k=quad*8+j] layout).
    long afr[2][8];
    {
        const unsigned char* Ab = Z + (size_t)(q0 + wm * 32) * 256;
#pragma unroll
        for (int mi = 0; mi < 2; ++mi)
#pragma unroll
            for (int kc = 0; kc < 8; ++kc)
                afr[mi][kc] = *(const long*)(Ab + (size_t)(mi * 16 + l15) * 256
                                             + kc * 32 + quad * 8);
    }

    // ---- stage tile t into lsB[buf]: unit u = c*64+lane (c = w*4+r);
    // u -> kp = u>>7, col = u&127; global 16B = col-row base + kp*16.
#define STAGE_B(t, buf)                                                       \
    {                                                                         \
        const unsigned char* Bb = Z + (size_t)(t) * 128 * 256;                \
        _Pragma("unroll")                                                     \
        for (int r = 0; r < 4; ++r) {                                         \
            const int c   = w * 4 + r;                                        \
            const int u   = c * 64 + lane;                                    \
            const int kp  = u >> 7;                                           \
            const int col = u & 127;                                          \
            gl_lds16(Bb + (size_t)col * 256 + kp * 16,                        \
                     &lsB[buf][(size_t)c * 1024]);                            \
        }                                                                     \
    }

    STAGE_B(t0, 0);

    float rs[2][4];
#pragma unroll
    for (int mi = 0; mi < 2; ++mi)
#pragma unroll
        for (int reg = 0; reg < 4; ++reg)
            rs[mi][reg] = 0.f;
    float dsum = 0.f;

    __syncthreads();                          // tile 0 ready

    const float C2L = 2.8853900817779268f;    // 2/ln2: exp(2x)=exp2(x*C2L)

    for (int jt = 0; jt < 32; ++jt) {
        const int buf = jt & 1;
        if (jt < 31) STAGE_B(t0 + jt + 1, buf ^ 1);

        float4v acc[2][4];
#pragma unroll
        for (int mi = 0; mi < 2; ++mi)
#pragma unroll
            for (int ni = 0; ni < 4; ++ni)
                acc[mi][ni] = (float4v){0.f, 0.f, 0.f, 0.f};

        const unsigned char* lb = &lsB[buf][0];
#pragma unroll
        for (int kc = 0; kc < 8; ++kc) {
            const int kseg = kc * 4 + quad;
            const int kp   = kseg >> 1;
            const int hf   = kseg & 1;
            long bfv[4];
#pragma unroll
            for (int ni = 0; ni < 4; ++ni)
                bfv[ni] = *(const long*)(lb +
                    ((size_t)kp * 128 + wn * 64 + ni * 16 + l15) * 16 + hf * 8);
#pragma unroll
            for (int mi = 0; mi < 2; ++mi)
#pragma unroll
                for (int ni = 0; ni < 4; ++ni)
                    acc[mi][ni] = __builtin_amdgcn_mfma_f32_16x16x32_fp8_fp8(
                        afr[mi][kc], bfv[ni], acc[mi][ni], 0, 0, 0);
        }

        if (t0 + jt == djt) {                 // cross-diagonal tile
#pragma unroll
            for (int mi = 0; mi < 2; ++mi)
#pragma unroll
                for (int ni = 0; ni < 4; ++ni)
#pragma unroll
                    for (int reg = 0; reg < 4; ++reg) {
                        const int rg = q0 + wm * 32 + mi * 16 + quad * 4 + reg;
                        const int cg = djt * 128 + wn * 64 + ni * 16 + l15;
                        if ((rg ^ 4096) == cg) dsum += acc[mi][ni][reg];
                    }
        }

#pragma unroll
        for (int mi = 0; mi < 2; ++mi)
#pragma unroll
            for (int reg = 0; reg < 4; ++reg) {
                float s = 0.f;
#pragma unroll
                for (int ni = 0; ni < 4; ++ni)
                    s += exp2f(acc[mi][ni][reg] * C2L);
                rs[mi][reg] += s;
            }

        __syncthreads();                      // next tile ready; buf reusable
    }

    // ---- epilogue: reduce rowsums over 16 col-lanes, atomics into S
    // (wn=0/1 waves cover the same rows -> atomics combine them).
#pragma unroll
    for (int mi = 0; mi < 2; ++mi)
#pragma unroll
        for (int reg = 0; reg < 4; ++reg) {
            float v = rs[mi][reg];
            v += __shfl_xor(v, 1); v += __shfl_xor(v, 2);
            v += __shfl_xor(v, 4); v += __shfl_xor(v, 8);
            rs[mi][reg] = v;
        }
    if (l15 == 0) {
        float* Sq = S + (size_t)batch * 8192 + q0 + wm * 32;
#pragma unroll
        for (int mi = 0; mi < 2; ++mi)
#pragma unroll
            for (int reg = 0; reg < 4; ++reg)
                atomicAdd(&Sq[mi * 16 + quad * 4 + reg], rs[mi][reg]);
    }
    {
        float dv = dsum;
        dv += __shfl_xor(dv, 1);  dv += __shfl_xor(dv, 2);
        dv += __shfl_xor(dv, 4);  dv += __shfl_xor(dv, 8);
        dv += __shfl_xor(dv, 16); dv += __shfl_xor(dv, 32);
        if (lane == 0 && dv != 0.f)
            atomicAdd(out, -0.25f * dv);      // 0.125 * (-2) * dsum
    }
#undef STAGE_B
}

// ---------------------------------------------------------------------------
// final: out += 0.125 * sum_{32768} log(S - e^2)
// ---------------------------------------------------------------------------
__global__ __launch_bounds__(256) void final_log_kernel(
    const float* __restrict__ S, float* __restrict__ out)
{
    __shared__ float red[4];
    const int tid  = threadIdx.x;
    const int w    = tid >> 6;
    const int lane = tid & 63;
    const float E2 = 7.3890560989306495f;
    float acc = 0.f;
    for (int i = blockIdx.x * 256 + tid; i < 32768; i += gridDim.x * 256)
        acc += logf(S[i] - E2);
    acc += __shfl_xor(acc, 1);  acc += __shfl_xor(acc, 2);
    acc += __shfl_xor(acc, 4);  acc += __shfl_xor(acc, 8);
    acc += __shfl_xor(acc, 16); acc += __shfl_xor(acc, 32);
    if (lane == 0) red[w] = acc;
    __syncthreads();
    if (tid == 0)
        atomicAdd(out, 0.125f * (red[0] + red[1] + red[2] + red[3]));
}

// ---------------------------------------------------------------------------
// Workspace (bytes), total ~34 MB:
//   [0,       131072)  S (4*8192 fp32)
//   [131072,  262144)  W1bf
//   [262144,  393216)  W2bf
//   [393216, 17170432) Xbf (bf16, 16.7MB) / zn8 (fp8, first 8.4MB; aliased —
//                      Xbf dead after proj1)
//   [17170432,33947648) Hbf
// ---------------------------------------------------------------------------
extern "C" void kernel_launch(void* const* d_in, const int* in_sizes, int n_in,
                              void* d_out, int out_size, void* d_ws, size_t ws_size,
                              hipStream_t stream)
{
    const float* X1 = (const float*)d_in[0];
    const float* X2 = (const float*)d_in[1];
    const float* W1 = (const float*)d_in[2];
    const float* b1 = (const float*)d_in[3];
    const float* W2 = (const float*)d_in[4];
    const float* b2 = (const float*)d_in[5];

    char* ws = (char*)d_ws;
    float* S    = (float*)(ws + 0);
    short* W1bf = (short*)(ws + 131072);
    short* W2bf = (short*)(ws + 262144);
    short* Xbf  = (short*)(ws + 393216);
    unsigned char* zn8 = (unsigned char*)(ws + 393216);
    short* Hbf  = (short*)(ws + 17170432);

    hipMemsetAsync(S, 0, 131072, stream);
    hipMemsetAsync(d_out, 0, sizeof(float), stream);

    convW_kernel<<<128, 256, 0, stream>>>(W1, W2, W1bf, W2bf);
    convX_kernel<<<8192, 256, 0, stream>>>(X1, X2, Xbf);
    proj1_kernel<<<256, 512, 0, stream>>>(Xbf, W1bf, b1, Hbf);
    proj2norm_kernel<<<256, 512, 0, stream>>>(Hbf, W2bf, b2, zn8);
    gram_fp8_kernel<<<512, 512, 0, stream>>>(zn8, S, (float*)d_out);
    final_log_kernel<<<64, 256, 0, stream>>>(S, (float*)d_out);
}

// Round 10
// 242.267 us; speedup vs baseline: 2.9204x; 1.0406x over previous
//
#include <hip/hip_runtime.h>
#include <math.h>

// ---------------------------------------------------------------------------
// Problem: B=4, L=4096, D=P=256, tau=0.5
// out = (1/8) * sum_{b,l} [ log(S1-e^2) + log(S2-e^2) - 4*d[b,l] ]
//   S[b,q] = sum_{m<2L} exp(2 * Zhat[b,q].Zhat[b,m]),  Zhat = [z1n; z2n]
// R10 gram: R9 skeleton (LDS dbuf, 2 blocks/CU) with two fixes:
//  (a) zn8 stores sqrt(2)*z -> MFMA acc = 2*dot directly; epilogue __expf
//      (R9 used plain exp2f = precise libm poly, ~20 VALU/elem -> 62% VALUBusy)
//  (b) MX-scaled mfma_scale_f32_16x16x128_f8f6f4 (scale=1): 2x rate, 4x fewer
//      instrs, B reads become b128 (R9's b64-from-16B-cells = structural
//      4-way bank conflict, 16.8M cycles).  Fallback to 16x16x32 if builtin
//      missing.
// ---------------------------------------------------------------------------

typedef __attribute__((ext_vector_type(8))) short short8;
typedef __attribute__((ext_vector_type(4))) short short4v;
typedef __attribute__((ext_vector_type(4))) float float4v;
typedef __attribute__((ext_vector_type(8))) int int8v;
typedef __attribute__((ext_vector_type(4))) int int4v;

__device__ __forceinline__ short f2bf(float f) {
    unsigned u = __builtin_bit_cast(unsigned, f);
    u += 0x7fffu + ((u >> 16) & 1u);          // RNE
    return (short)(u >> 16);
}

// manual fp32 -> fp8 e4m3fn (OCP), RNE.  |f| <= ~1.6 here (sqrt2 * normed z).
__device__ __forceinline__ unsigned char f2fp8(float f) {
    float af = fabsf(f);
    unsigned s = (__builtin_bit_cast(unsigned, f) >> 31) << 7;
    if (af < 0.015625f) {                     // subnormal (<2^-6); 8 rolls up
        int q = (int)rintf(af * 512.0f);
        return (unsigned char)(s | (unsigned)q);
    }
    unsigned au = __builtin_bit_cast(unsigned, af);
    au += 0x7FFFFu + ((au >> 20) & 1u);       // RNE at bit 20
    int e = (int)(au >> 23) - 127;
    unsigned m = (au >> 20) & 7u;
    return (unsigned char)(s | (unsigned)((e + 7) << 3) | m);
}

__device__ __forceinline__ void gl_lds16(const void* g, void* l) {
    __builtin_amdgcn_global_load_lds(
        (const __attribute__((address_space(1))) void*)g,
        (__attribute__((address_space(3))) void*)l, 16, 0, 0);
}

// ---------------------------------------------------------------------------
// 512-thread NT-GEMM core (verified R2/R3): C[RAxRB] = A*B^T, K=256, bf16.
// ---------------------------------------------------------------------------
template <int RA, int RB, int NWM>
__device__ __forceinline__ void gemm512_core(
    const short* __restrict__ A, const short* __restrict__ B,
    int arow0, int brow0, short* lsA, short* lsB, float4v acc[4][4])
{
    const int tid  = threadIdx.x;
    const int w    = tid >> 6;
    const int lane = tid & 63;
    const int wm   = w % NWM;
    const int wn   = w / NWM;
    constexpr int ACH = RA / 8;

    for (int kt = 0; kt < 4; ++kt) {
        const int kbase = kt * 64;
#pragma unroll
        for (int r = 0; r < 6; ++r) {
            const int c = w * 6 + r;
            if (c < ACH) {
                const int s   = c * 64 + lane;
                const int kc  = s / RA;
                const int row = s % RA;
                gl_lds16(A + (size_t)(arow0 + row) * 256 + kbase + kc * 8,
                         lsA + (size_t)c * 512);
            } else {
                const int s   = (c - ACH) * 64 + lane;
                const int kc  = s / RB;
                const int row = s % RB;
                gl_lds16(B + (size_t)(brow0 + row) * 256 + kbase + kc * 8,
                         lsB + (size_t)(c - ACH) * 512);
            }
        }
        __syncthreads();
#pragma unroll
        for (int ks = 0; ks < 2; ++ks) {
            const int kc = ks * 4 + (lane >> 4);
            short8 af[4], bfv[4];
#pragma unroll
            for (int mi = 0; mi < 4; ++mi)
                af[mi] = *(const short8*)(lsA + ((size_t)kc * RA + wm * 64 + mi * 16 + (lane & 15)) * 8);
#pragma unroll
            for (int ni = 0; ni < 4; ++ni)
                bfv[ni] = *(const short8*)(lsB + ((size_t)kc * RB + wn * 64 + ni * 16 + (lane & 15)) * 8);
#pragma unroll
            for (int mi = 0; mi < 4; ++mi)
#pragma unroll
                for (int ni = 0; ni < 4; ++ni)
                    acc[mi][ni] = __builtin_amdgcn_mfma_f32_16x16x32_bf16(
                        af[mi], bfv[ni], acc[mi][ni], 0, 0, 0);
        }
        __syncthreads();
    }
}

// ---------------------------------------------------------------------------
// fp32 -> bf16 converters
// ---------------------------------------------------------------------------
__global__ __launch_bounds__(256) void convX_kernel(
    const float* __restrict__ X1, const float* __restrict__ X2,
    short* __restrict__ dst)
{
    int i = blockIdx.x * 256 + threadIdx.x;
    const float* src = (i < 1048576) ? X1 : X2;
    int j = i & 1048575;
    float4v v = ((const float4v*)src)[j];
    short4v o;
    o.x = f2bf(v.x); o.y = f2bf(v.y); o.z = f2bf(v.z); o.w = f2bf(v.w);
    ((short4v*)dst)[i] = o;
}

__global__ __launch_bounds__(256) void convW_kernel(
    const float* __restrict__ W1, const float* __restrict__ W2,
    short* __restrict__ d1, short* __restrict__ d2)
{
    int i = blockIdx.x * 256 + threadIdx.x;
    const float* src = (i < 16384) ? W1 : W2;
    short* dst = (i < 16384) ? d1 : d2;
    int j = i & 16383;
    float4v v = ((const float4v*)src)[j];
    short4v o;
    o.x = f2bf(v.x); o.y = f2bf(v.y); o.z = f2bf(v.z); o.w = f2bf(v.w);
    ((short4v*)dst)[j] = o;
}

// ---------------------------------------------------------------------------
// proj1: H = elu(X*W1^T + b1) bf16, 32768x256, grid 256 x 512thr.
// ---------------------------------------------------------------------------
__global__ __launch_bounds__(512) void proj1_kernel(
    const short* __restrict__ Xbf, const short* __restrict__ W1bf,
    const float* __restrict__ b1, short* __restrict__ Hbf)
{
    __shared__ short lsA[8192];
    __shared__ short lsB[16384];
    const int arow0 = blockIdx.x * 128;
    float4v acc[4][4];
#pragma unroll
    for (int mi = 0; mi < 4; ++mi)
#pragma unroll
        for (int ni = 0; ni < 4; ++ni)
            acc[mi][ni] = (float4v){0.f, 0.f, 0.f, 0.f};

    gemm512_core<128, 256, 2>(Xbf, W1bf, arow0, 0, lsA, lsB, acc);

    const int tid  = threadIdx.x;
    const int w    = tid >> 6;
    const int lane = tid & 63;
    const int wm   = w % 2;
    const int wn   = w / 2;
    const int rowbase = arow0 + wm * 64 + (lane >> 4) * 4;
    const int colbase = wn * 64 + (lane & 15);
#pragma unroll
    for (int ni = 0; ni < 4; ++ni) {
        const int col = colbase + ni * 16;
        const float bv = b1[col];
#pragma unroll
        for (int mi = 0; mi < 4; ++mi)
#pragma unroll
            for (int reg = 0; reg < 4; ++reg) {
                const int row = rowbase + mi * 16 + reg;
                float v = acc[mi][ni][reg] + bv;
                v = (v > 0.f) ? v : expm1f(v);
                Hbf[(size_t)row * 256 + col] = f2bf(v);
            }
    }
}

// ---------------------------------------------------------------------------
// proj2 + normalize fused -> zn8 = fp8(sqrt2 * z/||z||) in [b][set][l][256].
// ---------------------------------------------------------------------------
__global__ __launch_bounds__(512) void proj2norm_kernel(
    const short* __restrict__ Hbf, const short* __restrict__ W2bf,
    const float* __restrict__ b2, unsigned char* __restrict__ zn8)
{
    __shared__ short lsA[8192];
    __shared__ short lsB[16384];
    __shared__ float rssq[4][128];
    __shared__ float rinv[128];
    const int arow0 = blockIdx.x * 128;
    float4v acc[4][4];
#pragma unroll
    for (int mi = 0; mi < 4; ++mi)
#pragma unroll
        for (int ni = 0; ni < 4; ++ni)
            acc[mi][ni] = (float4v){0.f, 0.f, 0.f, 0.f};

    gemm512_core<128, 256, 2>(Hbf, W2bf, arow0, 0, lsA, lsB, acc);

    const int tid  = threadIdx.x;
    const int w    = tid >> 6;
    const int lane = tid & 63;
    const int wm   = w % 2;
    const int wn   = w / 2;

#pragma unroll
    for (int ni = 0; ni < 4; ++ni) {
        const float bv = b2[wn * 64 + ni * 16 + (lane & 15)];
#pragma unroll
        for (int mi = 0; mi < 4; ++mi)
#pragma unroll
            for (int reg = 0; reg < 4; ++reg)
                acc[mi][ni][reg] += bv;
    }
    float ps[4][4];
#pragma unroll
    for (int mi = 0; mi < 4; ++mi)
#pragma unroll
        for (int reg = 0; reg < 4; ++reg) {
            float s = 0.f;
#pragma unroll
            for (int ni = 0; ni < 4; ++ni) {
                float v = acc[mi][ni][reg];
                s += v * v;
            }
            s += __shfl_xor(s, 1); s += __shfl_xor(s, 2);
            s += __shfl_xor(s, 4); s += __shfl_xor(s, 8);
            ps[mi][reg] = s;
        }
    if ((lane & 15) == 0) {
        const int g = lane >> 4;
#pragma unroll
        for (int mi = 0; mi < 4; ++mi)
#pragma unroll
            for (int reg = 0; reg < 4; ++reg)
                rssq[wn][wm * 64 + mi * 16 + g * 4 + reg] = ps[mi][reg];
    }
    __syncthreads();
    if (tid < 128) {
        float ssq = rssq[0][tid] + rssq[1][tid] + rssq[2][tid] + rssq[3][tid];
        // sqrt(2) folded in: gram acc becomes 2*dot directly
        rinv[tid] = 1.41421356237f / fmaxf(sqrtf(ssq), 1e-12f);
    }
    __syncthreads();

    const int r0  = arow0;
    const int set = r0 >> 14;
    const int bb  = (r0 >> 12) & 3;
    const int l0  = r0 & 4095;
    unsigned char* dst = zn8 + ((size_t)(bb * 2 + set) * 4096 + l0) * 256;
    const int colbase = wn * 64 + (lane & 15);
#pragma unroll
    for (int mi = 0; mi < 4; ++mi)
#pragma unroll
        for (int reg = 0; reg < 4; ++reg) {
            const int rl = wm * 64 + mi * 16 + (lane >> 4) * 4 + reg;
            const float inv = rinv[rl];
#pragma unroll
            for (int ni = 0; ni < 4; ++ni)
                dst[(size_t)rl * 256 + colbase + ni * 16] =
                    f2fp8(acc[mi][ni][reg] * inv);
        }
}

// ---------------------------------------------------------------------------
// FP8 flash-gram (R9 skeleton + MX-scaled MFMA): grid 512 x 512thr (8 waves),
// 2 blocks/CU.  Block = (batch, 128-row q-stripe, j-half of 32x128-col tiles).
// Wave grid: wm = w&3 (32-row band), wn = w>>2 (64-col half).
// LDS B tile [kp 0..15][col 0..127][16B], dbuf, staged via global_load_lds.
// Scaled path: K=128 per MFMA, A/B frag = 32 contiguous k-bytes per lane
// (k = quad*32 + j), read as 2x b128 (conflict-free 16B-stride class).
// acc = 2*dot (sqrt2 folded into zn8); epilogue __expf (native v_exp).
// ---------------------------------------------------------------------------
#if defined(__has_builtin)
#if __has_builtin(__builtin_amdgcn_mfma_scale_f32_16x16x128_f8f6f4)
#define HAVE_MX 1
#endif
#endif

__global__ __launch_bounds__(512, 2) void gram_fp8_kernel(
    const unsigned char* __restrict__ zn8, float* __restrict__ S,
    float* __restrict__ out)
{
    __shared__ unsigned char lsB[2][32768];   // [buf][kp][col][16]

    const int bx    = blockIdx.x;             // 0..511
    const int xcd   = bx & 7;                 // batch -> XCD pair {2b,2b+1}
    const int batch = xcd >> 1;
    const int sub   = (bx >> 3) * 2 + (xcd & 1);    // 0..127
    const int stripe = sub >> 1;              // 0..63: 128-row q-stripe
    const int half   = sub & 1;               // j-half
    const unsigned char* Z = zn8 + (size_t)batch * 2097152;
    const int q0 = stripe * 128;
    const int t0 = half * 32;                 // first 128-col j-tile
    const int djt = (q0 ^ 4096) >> 7;         // tile holding diagonal cols

    const int tid  = threadIdx.x;
    const int w    = tid >> 6;
    const int lane = tid & 63;
    const int wm   = w & 3;        // 32-row band
    const int wn   = w >> 2;       // 64-col half
    const int quad = lane >> 4;
    const int l15  = lane & 15;

#define STAGE_B(t, buf)                                                       \
    {                                                                         \
        const unsigned char* Bb = Z + (size_t)(t) * 128 * 256;                \
        _Pragma("unroll")                                                     \
        for (int r = 0; r < 4; ++r) {                                         \
            const int c   = w * 4 + r;                                        \
            const int u   = c * 64 + lane;                                    \
            const int kp  = u >> 7;                                           \
            const int col = u & 127;                                          \
            gl_lds16(Bb + (size_t)col * 256 + kp * 16,                        \
                     &lsB[buf][(size_t)c * 1024]);                            \
        }                                                                     \
    }

    float rs[2][4];
#pragma unroll
    for (int mi = 0; mi < 2; ++mi)
#pragma unroll
        for (int reg = 0; reg < 4; ++reg)
            rs[mi][reg] = 0.f;
    float dsum = 0.f;

#ifdef HAVE_MX
    // ---- A frags: 32 contiguous k-bytes (k = quad*32 + j) per (mi, ks)
    int8v afr[2][2];
    {
        const unsigned char* Ab = Z + (size_t)(q0 + wm * 32) * 256;
#pragma unroll
        for (int mi = 0; mi < 2; ++mi)
#pragma unroll
            for (int ks = 0; ks < 2; ++ks) {
                const unsigned char* p = Ab + (size_t)(mi * 16 + l15) * 256
                                         + ks * 128 + quad * 32;
                int4v lo = *(const int4v*)p;
                int4v hi = *(const int4v*)(p + 16);
                afr[mi][ks] = __builtin_shufflevector(lo, hi, 0,1,2,3,4,5,6,7);
            }
    }

    STAGE_B(t0, 0);
    __syncthreads();

    for (int jt = 0; jt < 32; ++jt) {
        const int buf = jt & 1;
        if (jt < 31) STAGE_B(t0 + jt + 1, buf ^ 1);

        float4v acc[2][4];
#pragma unroll
        for (int mi = 0; mi < 2; ++mi)
#pragma unroll
            for (int ni = 0; ni < 4; ++ni)
                acc[mi][ni] = (float4v){0.f, 0.f, 0.f, 0.f};

        const unsigned char* lb = &lsB[buf][0];
#pragma unroll
        for (int ks = 0; ks < 2; ++ks) {
            const int kp0 = ks * 8 + quad * 2;
            int8v bfv[4];
#pragma unroll
            for (int ni = 0; ni < 4; ++ni) {
                const unsigned char* p = lb +
                    ((size_t)kp0 * 128 + wn * 64 + ni * 16 + l15) * 16;
                int4v lo = *(const int4v*)p;
                int4v hi = *(const int4v*)(p + 2048);    // kp0+1 slot
                bfv[ni] = __builtin_shufflevector(lo, hi, 0,1,2,3,4,5,6,7);
            }
#pragma unroll
            for (int mi = 0; mi < 2; ++mi)
#pragma unroll
                for (int ni = 0; ni < 4; ++ni)
                    acc[mi][ni] = __builtin_amdgcn_mfma_scale_f32_16x16x128_f8f6f4(
                        afr[mi][ks], bfv[ni], acc[mi][ni],
                        0, 0,                     // cbsz=E4M3, blgp=E4M3
                        0, 0x7F7F7F7F,            // scale A = 1.0
                        0, 0x7F7F7F7F);           // scale B = 1.0
        }

        if (t0 + jt == djt) {                 // cross-diagonal tile
#pragma unroll
            for (int mi = 0; mi < 2; ++mi)
#pragma unroll
                for (int ni = 0; ni < 4; ++ni)
#pragma unroll
                    for (int reg = 0; reg < 4; ++reg) {
                        const int rg = q0 + wm * 32 + mi * 16 + quad * 4 + reg;
                        const int cg = djt * 128 + wn * 64 + ni * 16 + l15;
                        if ((rg ^ 4096) == cg) dsum += acc[mi][ni][reg];
                    }
        }

#pragma unroll
        for (int mi = 0; mi < 2; ++mi)
#pragma unroll
            for (int reg = 0; reg < 4; ++reg) {
                float s = 0.f;
#pragma unroll
                for (int ni = 0; ni < 4; ++ni)
                    s += __expf(acc[mi][ni][reg]);      // acc = 2*dot already
                rs[mi][reg] += s;
            }

        __syncthreads();
    }
#else
    // ---- fallback: non-scaled 16x16x32 fp8 (R9 structure, __expf epilogue)
    long afr[2][8];
    {
        const unsigned char* Ab = Z + (size_t)(q0 + wm * 32) * 256;
#pragma unroll
        for (int mi = 0; mi < 2; ++mi)
#pragma unroll
            for (int kc = 0; kc < 8; ++kc)
                afr[mi][kc] = *(const long*)(Ab + (size_t)(mi * 16 + l15) * 256
                                             + kc * 32 + quad * 8);
    }
    STAGE_B(t0, 0);
    __syncthreads();
    for (int jt = 0; jt < 32; ++jt) {
        const int buf = jt & 1;
        if (jt < 31) STAGE_B(t0 + jt + 1, buf ^ 1);
        float4v acc[2][4];
#pragma unroll
        for (int mi = 0; mi < 2; ++mi)
#pragma unroll
            for (int ni = 0; ni < 4; ++ni)
                acc[mi][ni] = (float4v){0.f, 0.f, 0.f, 0.f};
        const unsigned char* lb = &lsB[buf][0];
#pragma unroll
        for (int kc = 0; kc < 8; ++kc) {
            const int kseg = kc * 4 + quad;
            const int kp   = kseg >> 1;
            const int hf   = kseg & 1;
            long bfv[4];
#pragma unroll
            for (int ni = 0; ni < 4; ++ni)
                bfv[ni] = *(const long*)(lb +
                    ((size_t)kp * 128 + wn * 64 + ni * 16 + l15) * 16 + hf * 8);
#pragma unroll
            for (int mi = 0; mi < 2; ++mi)
#pragma unroll
                for (int ni = 0; ni < 4; ++ni)
                    acc[mi][ni] = __builtin_amdgcn_mfma_f32_16x16x32_fp8_fp8(
                        afr[mi][kc], bfv[ni], acc[mi][ni], 0, 0, 0);
        }
        if (t0 + jt == djt) {
#pragma unroll
            for (int mi = 0; mi < 2; ++mi)
#pragma unroll
                for (int ni = 0; ni < 4; ++ni)
#pragma unroll
                    for (int reg = 0; reg < 4; ++reg) {
                        const int rg = q0 + wm * 32 + mi * 16 + quad * 4 + reg;
                        const int cg = djt * 128 + wn * 64 + ni * 16 + l15;
                        if ((rg ^ 4096) == cg) dsum += acc[mi][ni][reg];
                    }
        }
#pragma unroll
        for (int mi = 0; mi < 2; ++mi)
#pragma unroll
            for (int reg = 0; reg < 4; ++reg) {
                float s = 0.f;
#pragma unroll
                for (int ni = 0; ni < 4; ++ni)
                    s += __expf(acc[mi][ni][reg]);
                rs[mi][reg] += s;
            }
        __syncthreads();
    }
#endif

    // ---- epilogue: reduce rowsums over 16 col-lanes, atomics into S.
#pragma unroll
    for (int mi = 0; mi < 2; ++mi)
#pragma unroll
        for (int reg = 0; reg < 4; ++reg) {
            float v = rs[mi][reg];
            v += __shfl_xor(v, 1); v += __shfl_xor(v, 2);
            v += __shfl_xor(v, 4); v += __shfl_xor(v, 8);
            rs[mi][reg] = v;
        }
    if (l15 == 0) {
        float* Sq = S + (size_t)batch * 8192 + q0 + wm * 32;
#pragma unroll
        for (int mi = 0; mi < 2; ++mi)
#pragma unroll
            for (int reg = 0; reg < 4; ++reg)
                atomicAdd(&Sq[mi * 16 + quad * 4 + reg], rs[mi][reg]);
    }
    {
        // dsum holds 2*(z1.z2) terms; total over blocks = 4*Sum d
        // need -0.5*Sum d  ->  factor -0.125
        float dv = dsum;
        dv += __shfl_xor(dv, 1);  dv += __shfl_xor(dv, 2);
        dv += __shfl_xor(dv, 4);  dv += __shfl_xor(dv, 8);
        dv += __shfl_xor(dv, 16); dv += __shfl_xor(dv, 32);
        if (lane == 0 && dv != 0.f)
            atomicAdd(out, -0.125f * dv);
    }
#undef STAGE_B
}

// ---------------------------------------------------------------------------
// final: out += 0.125 * sum_{32768} log(S - e^2)
// ---------------------------------------------------------------------------
__global__ __launch_bounds__(256) void final_log_kernel(
    const float* __restrict__ S, float* __restrict__ out)
{
    __shared__ float red[4];
    const int tid  = threadIdx.x;
    const int w    = tid >> 6;
    const int lane = tid & 63;
    const float E2 = 7.3890560989306495f;
    float acc = 0.f;
    for (int i = blockIdx.x * 256 + tid; i < 32768; i += gridDim.x * 256)
        acc += logf(S[i] - E2);
    acc += __shfl_xor(acc, 1);  acc += __shfl_xor(acc, 2);
    acc += __shfl_xor(acc, 4);  acc += __shfl_xor(acc, 8);
    acc += __shfl_xor(acc, 16); acc += __shfl_xor(acc, 32);
    if (lane == 0) red[w] = acc;
    __syncthreads();
    if (tid == 0)
        atomicAdd(out, 0.125f * (red[0] + red[1] + red[2] + red[3]));
}

// ---------------------------------------------------------------------------
// Workspace (bytes), total ~34 MB:
//   [0,       131072)  S (4*8192 fp32)
//   [131072,  262144)  W1bf
//   [262144,  393216)  W2bf
//   [393216, 17170432) Xbf (bf16, 16.7MB) / zn8 (fp8, first 8.4MB; aliased)
//   [17170432,33947648) Hbf
// ---------------------------------------------------------------------------
extern "C" void kernel_launch(void* const* d_in, const int* in_sizes, int n_in,
                              void* d_out, int out_size, void* d_ws, size_t ws_size,
                              hipStream_t stream)
{
    const float* X1 = (const float*)d_in[0];
    const float* X2 = (const float*)d_in[1];
    const float* W1 = (const float*)d_in[2];
    const float* b1 = (const float*)d_in[3];
    const float* W2 = (const float*)d_in[4];
    const float* b2 = (const float*)d_in[5];

    char* ws = (char*)d_ws;
    float* S    = (float*)(ws + 0);
    short* W1bf = (short*)(ws + 131072);
    short* W2bf = (short*)(ws + 262144);
    short* Xbf  = (short*)(ws + 393216);
    unsigned char* zn8 = (unsigned char*)(ws + 393216);
    short* Hbf  = (short*)(ws + 17170432);

    hipMemsetAsync(S, 0, 131072, stream);
    hipMemsetAsync(d_out, 0, sizeof(float), stream);

    convW_kernel<<<128, 256, 0, stream>>>(W1, W2, W1bf, W2bf);
    convX_kernel<<<8192, 256, 0, stream>>>(X1, X2, Xbf);
    proj1_kernel<<<256, 512, 0, stream>>>(Xbf, W1bf, b1, Hbf);
    proj2norm_kernel<<<256, 512, 0, stream>>>(Hbf, W2bf, b2, zn8);
    gram_fp8_kernel<<<512, 512, 0, stream>>>(zn8, S, (float*)d_out);
    final_log_kernel<<<64, 256, 0, stream>>>(S, (float*)d_out);
}

// Round 12
// 217.800 us; speedup vs baseline: 3.2485x; 1.1123x over previous
//
#include <hip/hip_runtime.h>
#include <math.h>

// ---------------------------------------------------------------------------
// Problem: B=4, L=4096, D=P=256, tau=0.5
// out = (1/8) * sum_{b,l} [ log(S1-e^2) + log(S2-e^2) - 4*d[b,l] ]
//   S[b,q] = sum_{m<2L} exp(2 * Zhat[b,q].Zhat[b,m]),  Zhat = [z1n; z2n]
// R11 (resubmitted after container infra failure): gram waves 64x64 (mi=4 ->
// each LDS B-read feeds 4 MFMAs; R10 was 2 -> LDS-read-pipe bound).
// 256-thr blocks (4 waves), A-in-regs fp8 (64 VGPR), MX-scaled MFMA.
// proj1/proj2: 64-row tiles, 256thr, 512 blocks -> 2 blocks/CU.
// ---------------------------------------------------------------------------

typedef __attribute__((ext_vector_type(8))) short short8;
typedef __attribute__((ext_vector_type(4))) short short4v;
typedef __attribute__((ext_vector_type(4))) float float4v;
typedef __attribute__((ext_vector_type(8))) int int8v;
typedef __attribute__((ext_vector_type(4))) int int4v;

__device__ __forceinline__ short f2bf(float f) {
    unsigned u = __builtin_bit_cast(unsigned, f);
    u += 0x7fffu + ((u >> 16) & 1u);          // RNE
    return (short)(u >> 16);
}

// manual fp32 -> fp8 e4m3fn (OCP), RNE.  |f| <= ~1.6 here (sqrt2 * normed z).
__device__ __forceinline__ unsigned char f2fp8(float f) {
    float af = fabsf(f);
    unsigned s = (__builtin_bit_cast(unsigned, f) >> 31) << 7;
    if (af < 0.015625f) {                     // subnormal (<2^-6); 8 rolls up
        int q = (int)rintf(af * 512.0f);
        return (unsigned char)(s | (unsigned)q);
    }
    unsigned au = __builtin_bit_cast(unsigned, af);
    au += 0x7FFFFu + ((au >> 20) & 1u);       // RNE at bit 20
    int e = (int)(au >> 23) - 127;
    unsigned m = (au >> 20) & 7u;
    return (unsigned char)(s | (unsigned)((e + 7) << 3) | m);
}

__device__ __forceinline__ void gl_lds16(const void* g, void* l) {
    __builtin_amdgcn_global_load_lds(
        (const __attribute__((address_space(1))) void*)g,
        (__attribute__((address_space(3))) void*)l, 16, 0, 0);
}

// ---------------------------------------------------------------------------
// 256-thread NT-GEMM core: C[64 x 256] = A[arow0..+64, 256) * B[0..256)^T.
// 4 waves, wave w covers cols w*64..+64, all 64 rows.  Single-buffered LDS
// (lsA 8KB + lsB 32KB), K=256 in 4 tiles.  bf16 16x16x32 MFMA.
// ---------------------------------------------------------------------------
__device__ __forceinline__ void gemm256_core(
    const short* __restrict__ A, const short* __restrict__ B,
    int arow0, short* lsA, short* lsB, float4v acc[4][4])
{
    const int tid  = threadIdx.x;
    const int w    = tid >> 6;
    const int lane = tid & 63;
    const int l15  = lane & 15;

    for (int kt = 0; kt < 4; ++kt) {
        const int kbase = kt * 64;
#pragma unroll
        for (int r = 0; r < 10; ++r) {
            const int c = w * 10 + r;         // 0..39 chunks (8 A + 32 B)
            if (c < 8) {
                const int s   = c * 64 + lane;
                const int kc  = s >> 6;
                const int row = s & 63;
                gl_lds16(A + (size_t)(arow0 + row) * 256 + kbase + kc * 8,
                         lsA + (size_t)c * 512);
            } else {
                const int s   = (c - 8) * 64 + lane;
                const int kc  = s >> 8;
                const int row = s & 255;
                gl_lds16(B + (size_t)row * 256 + kbase + kc * 8,
                         lsB + (size_t)(c - 8) * 512);
            }
        }
        __syncthreads();
#pragma unroll
        for (int ks = 0; ks < 2; ++ks) {
            const int kc = ks * 4 + (lane >> 4);
            short8 af[4], bfv[4];
#pragma unroll
            for (int mi = 0; mi < 4; ++mi)
                af[mi] = *(const short8*)(lsA + ((size_t)kc * 64 + mi * 16 + l15) * 8);
#pragma unroll
            for (int ni = 0; ni < 4; ++ni)
                bfv[ni] = *(const short8*)(lsB + ((size_t)kc * 256 + w * 64 + ni * 16 + l15) * 8);
#pragma unroll
            for (int mi = 0; mi < 4; ++mi)
#pragma unroll
                for (int ni = 0; ni < 4; ++ni)
                    acc[mi][ni] = __builtin_amdgcn_mfma_f32_16x16x32_bf16(
                        af[mi], bfv[ni], acc[mi][ni], 0, 0, 0);
        }
        __syncthreads();
    }
}

// ---------------------------------------------------------------------------
// fp32 -> bf16 converters
// ---------------------------------------------------------------------------
__global__ __launch_bounds__(256) void convX_kernel(
    const float* __restrict__ X1, const float* __restrict__ X2,
    short* __restrict__ dst)
{
    int i = blockIdx.x * 256 + threadIdx.x;
    const float* src = (i < 1048576) ? X1 : X2;
    int j = i & 1048575;
    float4v v = ((const float4v*)src)[j];
    short4v o;
    o.x = f2bf(v.x); o.y = f2bf(v.y); o.z = f2bf(v.z); o.w = f2bf(v.w);
    ((short4v*)dst)[i] = o;
}

__global__ __launch_bounds__(256) void convW_kernel(
    const float* __restrict__ W1, const float* __restrict__ W2,
    short* __restrict__ d1, short* __restrict__ d2)
{
    int i = blockIdx.x * 256 + threadIdx.x;
    const float* src = (i < 16384) ? W1 : W2;
    short* dst = (i < 16384) ? d1 : d2;
    int j = i & 16383;
    float4v v = ((const float4v*)src)[j];
    short4v o;
    o.x = f2bf(v.x); o.y = f2bf(v.y); o.z = f2bf(v.z); o.w = f2bf(v.w);
    ((short4v*)dst)[j] = o;
}

// ---------------------------------------------------------------------------
// proj1: H = elu(X*W1^T + b1) bf16, 32768x256, grid 512 x 256thr (64-row tiles).
// ---------------------------------------------------------------------------
__global__ __launch_bounds__(256, 4) void proj1_kernel(
    const short* __restrict__ Xbf, const short* __restrict__ W1bf,
    const float* __restrict__ b1, short* __restrict__ Hbf)
{
    __shared__ short lsA[4096];    // 64 x 64
    __shared__ short lsB[16384];   // 256 x 64
    const int arow0 = blockIdx.x * 64;
    float4v acc[4][4];
#pragma unroll
    for (int mi = 0; mi < 4; ++mi)
#pragma unroll
        for (int ni = 0; ni < 4; ++ni)
            acc[mi][ni] = (float4v){0.f, 0.f, 0.f, 0.f};

    gemm256_core(Xbf, W1bf, arow0, lsA, lsB, acc);

    const int tid  = threadIdx.x;
    const int w    = tid >> 6;
    const int lane = tid & 63;
    const int rowbase = arow0 + (lane >> 4) * 4;
    const int colbase = w * 64 + (lane & 15);
#pragma unroll
    for (int ni = 0; ni < 4; ++ni) {
        const int col = colbase + ni * 16;
        const float bv = b1[col];
#pragma unroll
        for (int mi = 0; mi < 4; ++mi)
#pragma unroll
            for (int reg = 0; reg < 4; ++reg) {
                const int row = rowbase + mi * 16 + reg;
                float v = acc[mi][ni][reg] + bv;
                v = (v > 0.f) ? v : expm1f(v);
                Hbf[(size_t)row * 256 + col] = f2bf(v);
            }
    }
}

// ---------------------------------------------------------------------------
// proj2 + normalize fused -> zn8 = fp8(sqrt2 * z/||z||) in [b][set][l][256].
// 64-row tiles, grid 512 x 256thr.
// ---------------------------------------------------------------------------
__global__ __launch_bounds__(256, 4) void proj2norm_kernel(
    const short* __restrict__ Hbf, const short* __restrict__ W2bf,
    const float* __restrict__ b2, unsigned char* __restrict__ zn8)
{
    __shared__ short lsA[4096];
    __shared__ short lsB[16384];
    __shared__ float rssq[4][64];
    __shared__ float rinv[64];
    const int arow0 = blockIdx.x * 64;
    float4v acc[4][4];
#pragma unroll
    for (int mi = 0; mi < 4; ++mi)
#pragma unroll
        for (int ni = 0; ni < 4; ++ni)
            acc[mi][ni] = (float4v){0.f, 0.f, 0.f, 0.f};

    gemm256_core(Hbf, W2bf, arow0, lsA, lsB, acc);

    const int tid  = threadIdx.x;
    const int w    = tid >> 6;
    const int lane = tid & 63;
    const int quad = lane >> 4;
    const int l15  = lane & 15;

#pragma unroll
    for (int ni = 0; ni < 4; ++ni) {
        const float bv = b2[w * 64 + ni * 16 + l15];
#pragma unroll
        for (int mi = 0; mi < 4; ++mi)
#pragma unroll
            for (int reg = 0; reg < 4; ++reg)
                acc[mi][ni][reg] += bv;
    }
    float ps[4][4];
#pragma unroll
    for (int mi = 0; mi < 4; ++mi)
#pragma unroll
        for (int reg = 0; reg < 4; ++reg) {
            float s = 0.f;
#pragma unroll
            for (int ni = 0; ni < 4; ++ni) {
                float v = acc[mi][ni][reg];
                s += v * v;
            }
            s += __shfl_xor(s, 1); s += __shfl_xor(s, 2);
            s += __shfl_xor(s, 4); s += __shfl_xor(s, 8);
            ps[mi][reg] = s;
        }
    if (l15 == 0) {
#pragma unroll
        for (int mi = 0; mi < 4; ++mi)
#pragma unroll
            for (int reg = 0; reg < 4; ++reg)
                rssq[w][mi * 16 + quad * 4 + reg] = ps[mi][reg];
    }
    __syncthreads();
    if (tid < 64) {
        float ssq = rssq[0][tid] + rssq[1][tid] + rssq[2][tid] + rssq[3][tid];
        // sqrt(2) folded in: gram acc becomes 2*dot directly
        rinv[tid] = 1.41421356237f / fmaxf(sqrtf(ssq), 1e-12f);
    }
    __syncthreads();

    const int r0  = arow0;                 // multiple of 64
    const int set = r0 >> 14;
    const int bb  = (r0 >> 12) & 3;
    const int l0  = r0 & 4095;
    unsigned char* dst = zn8 + ((size_t)(bb * 2 + set) * 4096 + l0) * 256;
    const int colbase = w * 64 + l15;
#pragma unroll
    for (int mi = 0; mi < 4; ++mi)
#pragma unroll
        for (int reg = 0; reg < 4; ++reg) {
            const int rl = mi * 16 + quad * 4 + reg;
            const float inv = rinv[rl];
#pragma unroll
            for (int ni = 0; ni < 4; ++ni)
                dst[(size_t)rl * 256 + colbase + ni * 16] =
                    f2fp8(acc[mi][ni][reg] * inv);
        }
}

// ---------------------------------------------------------------------------
// FP8 flash-gram R11: grid 512 x 256thr (4 waves), 2 blocks/CU target.
// Block = (batch, 128-row q-stripe, j-half of 32 x 128-col tiles).
// Wave grid 2 wm x 2 wn; wave = 64 rows x 64 cols (mi=4: 4x B-read reuse).
// A-frags in regs (fp8, 64 VGPR).  B tile [kp 0..15][col 0..127][16B] in
// LDS, dbuf 2x32KB, staged via global_load_lds(16B).
// acc = 2*dot (sqrt2 folded in zn8); epilogue __expf (native v_exp).
// ---------------------------------------------------------------------------
#if defined(__has_builtin)
#if __has_builtin(__builtin_amdgcn_mfma_scale_f32_16x16x128_f8f6f4)
#define HAVE_MX 1
#endif
#endif

__global__ __launch_bounds__(256, 2) void gram_fp8_kernel(
    const unsigned char* __restrict__ zn8, float* __restrict__ S,
    float* __restrict__ out)
{
    __shared__ unsigned char lsB[2][32768];   // [buf][kp][col][16]

    const int bx    = blockIdx.x;             // 0..511
    const int xcd   = bx & 7;                 // batch -> XCD pair {2b,2b+1}
    const int batch = xcd >> 1;
    const int sub   = (bx >> 3) * 2 + (xcd & 1);    // 0..127
    const int stripe = sub >> 1;              // 0..63: 128-row q-stripe
    const int half   = sub & 1;               // j-half
    const unsigned char* Z = zn8 + (size_t)batch * 2097152;
    const int q0 = stripe * 128;
    const int t0 = half * 32;                 // first 128-col j-tile
    const int djt = (q0 ^ 4096) >> 7;         // tile holding diagonal cols

    const int tid  = threadIdx.x;
    const int w    = tid >> 6;
    const int lane = tid & 63;
    const int wm   = w & 1;        // 64-row band
    const int wn   = w >> 1;       // 64-col half
    const int quad = lane >> 4;
    const int l15  = lane & 15;

#define STAGE_B(t, buf)                                                       \
    {                                                                         \
        const unsigned char* Bb = Z + (size_t)(t) * 128 * 256;                \
        _Pragma("unroll")                                                     \
        for (int r = 0; r < 8; ++r) {                                         \
            const int c   = w * 8 + r;                                        \
            const int u   = c * 64 + lane;                                    \
            const int kp  = u >> 7;                                           \
            const int col = u & 127;                                          \
            gl_lds16(Bb + (size_t)col * 256 + kp * 16,                        \
                     &lsB[buf][(size_t)c * 1024]);                            \
        }                                                                     \
    }

    float rs[4][4];
#pragma unroll
    for (int mi = 0; mi < 4; ++mi)
#pragma unroll
        for (int reg = 0; reg < 4; ++reg)
            rs[mi][reg] = 0.f;
    float dsum = 0.f;

#ifdef HAVE_MX
    // ---- A frags: 32 contiguous k-bytes (k = quad*32 + j) per (mi, ks)
    int8v afr[4][2];
    {
        const unsigned char* Ab = Z + (size_t)(q0 + wm * 64) * 256;
#pragma unroll
        for (int mi = 0; mi < 4; ++mi)
#pragma unroll
            for (int ks = 0; ks < 2; ++ks) {
                const unsigned char* p = Ab + (size_t)(mi * 16 + l15) * 256
                                         + ks * 128 + quad * 32;
                int4v lo = *(const int4v*)p;
                int4v hi = *(const int4v*)(p + 16);
                afr[mi][ks] = __builtin_shufflevector(lo, hi, 0,1,2,3,4,5,6,7);
            }
    }

    STAGE_B(t0, 0);
    __syncthreads();

    for (int jt = 0; jt < 32; ++jt) {
        const int buf = jt & 1;
        if (jt < 31) STAGE_B(t0 + jt + 1, buf ^ 1);

        float4v acc[4][4];
#pragma unroll
        for (int mi = 0; mi < 4; ++mi)
#pragma unroll
            for (int ni = 0; ni < 4; ++ni)
                acc[mi][ni] = (float4v){0.f, 0.f, 0.f, 0.f};

        const unsigned char* lb = &lsB[buf][0];
#pragma unroll
        for (int ks = 0; ks < 2; ++ks) {
            const int kp0 = ks * 8 + quad * 2;
            int8v bfv[4];
#pragma unroll
            for (int ni = 0; ni < 4; ++ni) {
                const unsigned char* p = lb +
                    ((size_t)kp0 * 128 + wn * 64 + ni * 16 + l15) * 16;
                int4v lo = *(const int4v*)p;
                int4v hi = *(const int4v*)(p + 2048);    // kp0+1 slot
                bfv[ni] = __builtin_shufflevector(lo, hi, 0,1,2,3,4,5,6,7);
            }
#pragma unroll
            for (int mi = 0; mi < 4; ++mi)
#pragma unroll
                for (int ni = 0; ni < 4; ++ni)
                    acc[mi][ni] = __builtin_amdgcn_mfma_scale_f32_16x16x128_f8f6f4(
                        afr[mi][ks], bfv[ni], acc[mi][ni],
                        0, 0,                     // cbsz=E4M3, blgp=E4M3
                        0, 0x7F7F7F7F,            // scale A = 1.0
                        0, 0x7F7F7F7F);           // scale B = 1.0
        }

        if (t0 + jt == djt) {                 // cross-diagonal tile
#pragma unroll
            for (int mi = 0; mi < 4; ++mi)
#pragma unroll
                for (int ni = 0; ni < 4; ++ni)
#pragma unroll
                    for (int reg = 0; reg < 4; ++reg) {
                        const int rg = q0 + wm * 64 + mi * 16 + quad * 4 + reg;
                        const int cg = djt * 128 + wn * 64 + ni * 16 + l15;
                        if ((rg ^ 4096) == cg) dsum += acc[mi][ni][reg];
                    }
        }

#pragma unroll
        for (int mi = 0; mi < 4; ++mi)
#pragma unroll
            for (int reg = 0; reg < 4; ++reg) {
                float s = 0.f;
#pragma unroll
                for (int ni = 0; ni < 4; ++ni)
                    s += __expf(acc[mi][ni][reg]);      // acc = 2*dot already
                rs[mi][reg] += s;
            }

        __syncthreads();
    }
#else
    // ---- fallback: non-scaled 16x16x32 fp8, same shape
    long afr[4][8];
    {
        const unsigned char* Ab = Z + (size_t)(q0 + wm * 64) * 256;
#pragma unroll
        for (int mi = 0; mi < 4; ++mi)
#pragma unroll
            for (int kc = 0; kc < 8; ++kc)
                afr[mi][kc] = *(const long*)(Ab + (size_t)(mi * 16 + l15) * 256
                                             + kc * 32 + quad * 8);
    }
    STAGE_B(t0, 0);
    __syncthreads();
    for (int jt = 0; jt < 32; ++jt) {
        const int buf = jt & 1;
        if (jt < 31) STAGE_B(t0 + jt + 1, buf ^ 1);
        float4v acc[4][4];
#pragma unroll
        for (int mi = 0; mi < 4; ++mi)
#pragma unroll
            for (int ni = 0; ni < 4; ++ni)
                acc[mi][ni] = (float4v){0.f, 0.f, 0.f, 0.f};
        const unsigned char* lb = &lsB[buf][0];
#pragma unroll
        for (int kc = 0; kc < 8; ++kc) {
            const int kseg = kc * 4 + quad;
            const int kp   = kseg >> 1;
            const int hf   = kseg & 1;
            long bfv[4];
#pragma unroll
            for (int ni = 0; ni < 4; ++ni)
                bfv[ni] = *(const long*)(lb +
                    ((size_t)kp * 128 + wn * 64 + ni * 16 + l15) * 16 + hf * 8);
#pragma unroll
            for (int mi = 0; mi < 4; ++mi)
#pragma unroll
                for (int ni = 0; ni < 4; ++ni)
                    acc[mi][ni] = __builtin_amdgcn_mfma_f32_16x16x32_fp8_fp8(
                        afr[mi][kc], bfv[ni], acc[mi][ni], 0, 0, 0);
        }
        if (t0 + jt == djt) {
#pragma unroll
            for (int mi = 0; mi < 4; ++mi)
#pragma unroll
                for (int ni = 0; ni < 4; ++ni)
#pragma unroll
                    for (int reg = 0; reg < 4; ++reg) {
                        const int rg = q0 + wm * 64 + mi * 16 + quad * 4 + reg;
                        const int cg = djt * 128 + wn * 64 + ni * 16 + l15;
                        if ((rg ^ 4096) == cg) dsum += acc[mi][ni][reg];
                    }
        }
#pragma unroll
        for (int mi = 0; mi < 4; ++mi)
#pragma unroll
            for (int reg = 0; reg < 4; ++reg) {
                float s = 0.f;
#pragma unroll
                for (int ni = 0; ni < 4; ++ni)
                    s += __expf(acc[mi][ni][reg]);
                rs[mi][reg] += s;
            }
        __syncthreads();
    }
#endif

    // ---- epilogue: reduce rowsums over 16 col-lanes, atomics into S.
    // (wn=0/1 waves cover the same rows; atomics combine.)
#pragma unroll
    for (int mi = 0; mi < 4; ++mi)
#pragma unroll
        for (int reg = 0; reg < 4; ++reg) {
            float v = rs[mi][reg];
            v += __shfl_xor(v, 1); v += __shfl_xor(v, 2);
            v += __shfl_xor(v, 4); v += __shfl_xor(v, 8);
            rs[mi][reg] = v;
        }
    if (l15 == 0) {
        float* Sq = S + (size_t)batch * 8192 + q0 + wm * 64;
#pragma unroll
        for (int mi = 0; mi < 4; ++mi)
#pragma unroll
            for (int reg = 0; reg < 4; ++reg)
                atomicAdd(&Sq[mi * 16 + quad * 4 + reg], rs[mi][reg]);
    }
    {
        // dsum holds 2*(z1.z2) terms; blocks collectively see 4*Sum d;
        // need -0.5*Sum d -> factor -0.125
        float dv = dsum;
        dv += __shfl_xor(dv, 1);  dv += __shfl_xor(dv, 2);
        dv += __shfl_xor(dv, 4);  dv += __shfl_xor(dv, 8);
        dv += __shfl_xor(dv, 16); dv += __shfl_xor(dv, 32);
        if (lane == 0 && dv != 0.f)
            atomicAdd(out, -0.125f * dv);
    }
#undef STAGE_B
}

// ---------------------------------------------------------------------------
// final: out += 0.125 * sum_{32768} log(S - e^2)
// ---------------------------------------------------------------------------
__global__ __launch_bounds__(256) void final_log_kernel(
    const float* __restrict__ S, float* __restrict__ out)
{
    __shared__ float red[4];
    const int tid  = threadIdx.x;
    const int w    = tid >> 6;
    const int lane = tid & 63;
    const float E2 = 7.3890560989306495f;
    float acc = 0.f;
    for (int i = blockIdx.x * 256 + tid; i < 32768; i += gridDim.x * 256)
        acc += logf(S[i] - E2);
    acc += __shfl_xor(acc, 1);  acc += __shfl_xor(acc, 2);
    acc += __shfl_xor(acc, 4);  acc += __shfl_xor(acc, 8);
    acc += __shfl_xor(acc, 16); acc += __shfl_xor(acc, 32);
    if (lane == 0) red[w] = acc;
    __syncthreads();
    if (tid == 0)
        atomicAdd(out, 0.125f * (red[0] + red[1] + red[2] + red[3]));
}

// ---------------------------------------------------------------------------
// Workspace (bytes), total ~34 MB:
//   [0,       131072)  S (4*8192 fp32)
//   [131072,  262144)  W1bf
//   [262144,  393216)  W2bf
//   [393216, 17170432) Xbf (bf16, 16.7MB) / zn8 (fp8, first 8.4MB; aliased)
//   [17170432,33947648) Hbf
// ---------------------------------------------------------------------------
extern "C" void kernel_launch(void* const* d_in, const int* in_sizes, int n_in,
                              void* d_out, int out_size, void* d_ws, size_t ws_size,
                              hipStream_t stream)
{
    const float* X1 = (const float*)d_in[0];
    const float* X2 = (const float*)d_in[1];
    const float* W1 = (const float*)d_in[2];
    const float* b1 = (const float*)d_in[3];
    const float* W2 = (const float*)d_in[4];
    const float* b2 = (const float*)d_in[5];

    char* ws = (char*)d_ws;
    float* S    = (float*)(ws + 0);
    short* W1bf = (short*)(ws + 131072);
    short* W2bf = (short*)(ws + 262144);
    short* Xbf  = (short*)(ws + 393216);
    unsigned char* zn8 = (unsigned char*)(ws + 393216);
    short* Hbf  = (short*)(ws + 17170432);

    hipMemsetAsync(S, 0, 131072, stream);
    hipMemsetAsync(d_out, 0, sizeof(float), stream);

    convW_kernel<<<128, 256, 0, stream>>>(W1, W2, W1bf, W2bf);
    convX_kernel<<<8192, 256, 0, stream>>>(X1, X2, Xbf);
    proj1_kernel<<<512, 256, 0, stream>>>(Xbf, W1bf, b1, Hbf);
    proj2norm_kernel<<<512, 256, 0, stream>>>(Hbf, W2bf, b2, zn8);
    gram_fp8_kernel<<<512, 256, 0, stream>>>(zn8, S, (float*)d_out);
    final_log_kernel<<<64, 256, 0, stream>>>(S, (float*)d_out);
}